// Round 6
// baseline (181.982 us; speedup 1.0000x reference)
//
#include <hip/hip_runtime.h>
#include <hip/hip_bf16.h>
#include <stdint.h>
#include <math.h>

typedef __bf16 bf16_t;
typedef __attribute__((ext_vector_type(8))) __bf16 bf16x8;
typedef __attribute__((ext_vector_type(4))) __bf16 bf16x4;
typedef __attribute__((ext_vector_type(4))) float f32x4;
typedef __attribute__((ext_vector_type(16))) float f32x16;
typedef unsigned int uint2v __attribute__((ext_vector_type(2)));

static constexpr int S = 2048;
static constexpr int DM = 2048;
static constexpr int NH = 16;
static constexpr int NKV = 4;
static constexpr int DH = 128;

#define MFMA16(a, b, c) __builtin_amdgcn_mfma_f32_16x16x32_bf16((a), (b), (c), 0, 0, 0)
#define MFMA32(a, b, c) __builtin_amdgcn_mfma_f32_32x32x16_bf16((a), (b), (c), 0, 0, 0)

__device__ __forceinline__ void gload_lds16(const void* g, void* l) {
  __builtin_amdgcn_global_load_lds((__attribute__((address_space(1))) void*)(g),
                                   (__attribute__((address_space(3))) void*)(l), 16, 0, 0);
}

template <int N>
__device__ __forceinline__ void wait_vmcnt() {
  asm volatile("s_waitcnt vmcnt(%0)" :: "n"(N) : "memory");
}
__device__ __forceinline__ void wait_lgkm0() {
  asm volatile("s_waitcnt lgkmcnt(0)" ::: "memory");
}

__device__ __forceinline__ unsigned cvtpk(float lo, float hi) {
  unsigned r;
  asm("v_cvt_pk_bf16_f32 %0, %1, %2" : "=v"(r) : "v"(lo), "v"(hi));
  return r;
}
__device__ __forceinline__ void plswap2(unsigned& a, unsigned& b) {
  uint2v r = __builtin_amdgcn_permlane32_swap(a, b, false, false);
  a = r[0]; b = r[1];
}
__device__ __forceinline__ float swapred_max(float x) {
  uint2v r = __builtin_amdgcn_permlane32_swap(__float_as_uint(x), __float_as_uint(x), false, false);
  return fmaxf(__uint_as_float(r[0]), __uint_as_float(r[1]));
}
__device__ __forceinline__ float swapred_sum(float x) {
  uint2v r = __builtin_amdgcn_permlane32_swap(__float_as_uint(x), __float_as_uint(x), false, false);
  return __uint_as_float(r[0]) + __uint_as_float(r[1]);
}
__device__ __forceinline__ bf16x8 packfrag(float a0, float a1, float a2, float a3,
                                           float a4, float a5, float a6, float a7) {
  unsigned w0 = cvtpk(a0, a1), w1 = cvtpk(a2, a3);
  unsigned w2 = cvtpk(a4, a5), w3 = cvtpk(a6, a7);
  plswap2(w0, w2); plswap2(w1, w3);
  union { unsigned u[4]; bf16x8 v; } u;
  u.u[0] = w0; u.u[1] = w1; u.u[2] = w2; u.u[3] = w3;
  return u.v;
}

// 34 chunks/head, (qb<<2)|ci, descending tile count (chunk = up to 10 KV-tiles)
__device__ const unsigned char attn_map[34] = {
  60, 61, 62, 56, 57, 58, 52, 53, 48, 49, 44, 45, 40, 41, 36, 37, 32,
  28, 24, 20, 16, 12, 33, 54, 8, 29, 50, 4, 25, 46, 0, 21, 42, 63};
// partial-slot base per qb (split qbs 5..15; 29 slots/head)
__device__ const unsigned char sbase[16] = {0,0,0,0,0, 0,2,4,6,8, 10,13,16,19,22, 25};

// ---- RoPE table: [S][64] float2 {sin, cos}; angle = p * base^(-j/64)
__global__ void rope_table_k(float2* __restrict__ tab) {
  int p = blockIdx.x;
  int j = threadIdx.x;
  double inv = exp2(-(double)j * 13.287712379549449 / 64.0);  // log2(10000)
  double ang = (double)p * inv;
  tab[p * 64 + j] = make_float2((float)sin(ang), (float)cos(ang));
}

// ---- fused f32 -> bf16 convert of Xq, Xk, Xv
__global__ void cvt3_k(const float* __restrict__ Xq, const float* __restrict__ Xk,
                       const float* __restrict__ Xv, bf16_t* __restrict__ xq,
                       bf16_t* __restrict__ xk, bf16_t* __restrict__ xv) {
  int i = (blockIdx.x * 256 + threadIdx.x) * 4;
  const float* in; bf16_t* out; int off;
  if (i < 4194304) { in = Xq; out = xq; off = i; }
  else if (i < 8388608) { in = Xk; out = xk; off = i - 4194304; }
  else { in = Xv; out = xv; off = i - 8388608; }
  f32x4 v = *(const f32x4*)(in + off);
  bf16x4 o;
  o[0] = (bf16_t)v[0]; o[1] = (bf16_t)v[1]; o[2] = (bf16_t)v[2]; o[3] = (bf16_t)v[3];
  *(bf16x4*)(out + off) = o;
}

// ---- weight transpose+convert
__global__ void transpose_w_k(const float* __restrict__ in, bf16_t* __restrict__ out,
                              int R, int C, int rb, int cb, int ldo) {
  __shared__ float tile[32][33];
  int b = blockIdx.z;
  int c0 = blockIdx.x * 32, r0 = blockIdx.y * 32;
  int tx = threadIdx.x, ty = threadIdx.y;  // 32 x 8
  const float* src = in + (size_t)b * R * C;
  #pragma unroll
  for (int j = 0; j < 32; j += 8)
    tile[ty + j][tx] = src[(size_t)(r0 + ty + j) * C + c0 + tx];
  __syncthreads();
  #pragma unroll
  for (int j = 0; j < 32; j += 8) {
    int c = c0 + ty + j;
    int r = r0 + tx;
    out[(size_t)(b * rb + c) * ldo + b * cb + r] = (bf16_t)tile[tx][ty + j];
  }
}

// ---- fused WK+WV transpose
__global__ void transpose_wkv_k(const float* __restrict__ WK, const float* __restrict__ WV,
                                bf16_t* __restrict__ wkT, bf16_t* __restrict__ wvT) {
  __shared__ float tile[32][33];
  int z = blockIdx.z;
  int b = z & 3;
  const float* in = (z < 4) ? WK : WV;
  bf16_t* out = (z < 4) ? wkT : wvT;
  int c0 = blockIdx.x * 32, r0 = blockIdx.y * 32;
  int tx = threadIdx.x, ty = threadIdx.y;
  const float* src = in + (size_t)b * 2048 * 128;
  #pragma unroll
  for (int j = 0; j < 32; j += 8)
    tile[ty + j][tx] = src[(size_t)(r0 + ty + j) * 128 + c0 + tx];
  __syncthreads();
  #pragma unroll
  for (int j = 0; j < 32; j += 8) {
    int c = c0 + ty + j;
    int r = r0 + tx;
    out[(size_t)(b * 128 + c) * 2048 + r] = (bf16_t)tile[tx][ty + j];
  }
}

// ---- fused vectorized NeoX rotary on Q [16][S][128] and K [4][S][128]
__global__ void rope_qk_k(bf16_t* __restrict__ Qb, bf16_t* __restrict__ Kb,
                          const float2* __restrict__ tab, float qscale) {
  int tid = blockIdx.x * 256 + threadIdx.x;
  int row = tid >> 4;
  int i = (tid & 15) * 4;
  bf16_t* base; float scale;
  if (row < NH * S) { base = Qb + (size_t)row * DH; scale = qscale; }
  else { base = Kb + (size_t)(row - NH * S) * DH; scale = 1.0f; }
  int p = row & (S - 1);
  bf16x4 lo = *(bf16x4*)(base + i);
  bf16x4 hi = *(bf16x4*)(base + i + 64);
  float4 t0 = *(const float4*)(tab + p * 64 + i);
  float4 t1 = *(const float4*)(tab + p * 64 + i + 2);
  float sv[4] = {t0.x, t0.z, t1.x, t1.z};
  float cv[4] = {t0.y, t0.w, t1.y, t1.w};
  bf16x4 nlo, nhi;
  #pragma unroll
  for (int j = 0; j < 4; ++j) {
    float a = (float)lo[j], b = (float)hi[j];
    nlo[j] = (bf16_t)((a * cv[j] - b * sv[j]) * scale);
    nhi[j] = (bf16_t)((b * cv[j] + a * sv[j]) * scale);
  }
  *(bf16x4*)(base + i) = nlo;
  *(bf16x4*)(base + i + 64) = nhi;
}

// ---- fused QKV projection GEMM (BM=128, BN=64, BK=64, 768 blocks)
__global__ __launch_bounds__(256)
void proj_gemm_k(const bf16_t* __restrict__ xq, const bf16_t* __restrict__ xk,
                 const bf16_t* __restrict__ xv, const bf16_t* __restrict__ wqT,
                 const bf16_t* __restrict__ wkT, const bf16_t* __restrict__ wvT,
                 const float* __restrict__ bQ, const float* __restrict__ bK,
                 const float* __restrict__ bV, bf16_t* __restrict__ Qb,
                 bf16_t* __restrict__ Kb, bf16_t* __restrict__ Vt) {
  const int nb = blockIdx.x;
  const int m0 = blockIdx.y * 128;
  const bf16_t* A; const bf16_t* B; const float* bias; bf16_t* dst; int ncol0;
  bool vmode = false;
  if (nb < 32)      { A = xq; B = wqT; bias = bQ; dst = Qb; ncol0 = nb * 64; }
  else if (nb < 40) { A = xk; B = wkT; bias = bK; dst = Kb; ncol0 = (nb - 32) * 64; }
  else              { A = xv; B = wvT; bias = bV; dst = Vt; ncol0 = (nb - 40) * 64; vmode = true; }
  const int K = 2048;
  const int t = threadIdx.x;
  const int lane = t & 63, w = t >> 6;
  const int l15 = lane & 15, lg = lane >> 4;
  const int wr = (w >> 1) * 64, wc = (w & 1) * 32;

  __shared__ bf16_t lA[2][128 * 64];
  __shared__ bf16_t lB[2][64 * 64];

  f32x4 acc[4][2] = {};
  const int srow = t >> 3;
  const int sslot = t & 7;

  auto stage = [&](int buf, int kt) {
    #pragma unroll
    for (int i = 0; i < 4; ++i) {
      int row = i * 32 + srow;
      int ss = sslot ^ (row & 7);
      gload_lds16(A + (size_t)(m0 + row) * K + kt * 64 + ss * 8,
                  (void*)(&lA[buf][0] + i * 2048 + t * 8));
    }
    #pragma unroll
    for (int i = 0; i < 2; ++i) {
      int row = i * 32 + srow;
      int ss = sslot ^ (row & 7);
      gload_lds16(B + (size_t)(ncol0 + row) * K + kt * 64 + ss * 8,
                  (void*)(&lB[buf][0] + i * 2048 + t * 8));
    }
  };

  const int nk = K >> 6;
  stage(0, 0);
  for (int kt = 0; kt < nk; ++kt) {
    const int cur = kt & 1;
    if (kt + 1 < nk) {
      stage(cur ^ 1, kt + 1);
      wait_vmcnt<6>();
    } else {
      wait_vmcnt<0>();
    }
    __builtin_amdgcn_s_barrier();
    #pragma unroll
    for (int kk = 0; kk < 2; ++kk) {
      bf16x8 af[4], bfv[2];
      #pragma unroll
      for (int f = 0; f < 4; ++f) {
        int row = wr + f * 16 + l15;
        int slot = kk * 4 + lg;
        af[f] = *(const bf16x8*)(&lA[cur][0] + row * 64 + ((slot ^ (row & 7)) * 8));
      }
      #pragma unroll
      for (int f = 0; f < 2; ++f) {
        int row = wc + f * 16 + l15;
        int slot = kk * 4 + lg;
        bfv[f] = *(const bf16x8*)(&lB[cur][0] + row * 64 + ((slot ^ (row & 7)) * 8));
      }
      #pragma unroll
      for (int fm = 0; fm < 4; ++fm)
        #pragma unroll
        for (int fn = 0; fn < 2; ++fn)
          acc[fm][fn] = MFMA16(af[fm], bfv[fn], acc[fm][fn]);
    }
    wait_lgkm0();
    __builtin_amdgcn_s_barrier();
  }

  #pragma unroll
  for (int fm = 0; fm < 4; ++fm) {
    int rowb = m0 + wr + fm * 16 + lg * 4;
    #pragma unroll
    for (int fn = 0; fn < 2; ++fn) {
      int col = ncol0 + wc + fn * 16 + l15;
      float bb = bias[col];
      if (vmode) {
        bf16x4 pk;
        #pragma unroll
        for (int r = 0; r < 4; ++r) pk[r] = (bf16_t)(acc[fm][fn][r] + bb);
        *(bf16x4*)(dst + (size_t)col * S + rowb) = pk;
      } else {
        #pragma unroll
        for (int r = 0; r < 4; ++r) {
          float v = acc[fm][fn][r] + bb;
          dst[((size_t)(col >> 7) * S + (rowb + r)) * DH + (col & 127)] = (bf16_t)v;
        }
      }
    }
  }
}

// ---- O-projection GEMM
__global__ __launch_bounds__(256)
void gemm_o_k(const bf16_t* __restrict__ A, const bf16_t* __restrict__ B,
              const float* __restrict__ bias, float* __restrict__ Cout) {
  const int ncol0 = blockIdx.x * 64;
  const int m0 = blockIdx.y * 128;
  const int K = 2048;
  const int t = threadIdx.x;
  const int lane = t & 63, w = t >> 6;
  const int l15 = lane & 15, lg = lane >> 4;
  const int wr = (w >> 1) * 64, wc = (w & 1) * 32;

  __shared__ bf16_t lA[2][128 * 64];
  __shared__ bf16_t lB[2][64 * 64];

  f32x4 acc[4][2] = {};
  const int srow = t >> 3;
  const int sslot = t & 7;

  auto stage = [&](int buf, int kt) {
    #pragma unroll
    for (int i = 0; i < 4; ++i) {
      int row = i * 32 + srow;
      int ss = sslot ^ (row & 7);
      gload_lds16(A + (size_t)(m0 + row) * K + kt * 64 + ss * 8,
                  (void*)(&lA[buf][0] + i * 2048 + t * 8));
    }
    #pragma unroll
    for (int i = 0; i < 2; ++i) {
      int row = i * 32 + srow;
      int ss = sslot ^ (row & 7);
      gload_lds16(B + (size_t)(ncol0 + row) * K + kt * 64 + ss * 8,
                  (void*)(&lB[buf][0] + i * 2048 + t * 8));
    }
  };

  const int nk = K >> 6;
  stage(0, 0);
  for (int kt = 0; kt < nk; ++kt) {
    const int cur = kt & 1;
    if (kt + 1 < nk) {
      stage(cur ^ 1, kt + 1);
      wait_vmcnt<6>();
    } else {
      wait_vmcnt<0>();
    }
    __builtin_amdgcn_s_barrier();
    #pragma unroll
    for (int kk = 0; kk < 2; ++kk) {
      bf16x8 af[4], bfv[2];
      #pragma unroll
      for (int f = 0; f < 4; ++f) {
        int row = wr + f * 16 + l15;
        int slot = kk * 4 + lg;
        af[f] = *(const bf16x8*)(&lA[cur][0] + row * 64 + ((slot ^ (row & 7)) * 8));
      }
      #pragma unroll
      for (int f = 0; f < 2; ++f) {
        int row = wc + f * 16 + l15;
        int slot = kk * 4 + lg;
        bfv[f] = *(const bf16x8*)(&lB[cur][0] + row * 64 + ((slot ^ (row & 7)) * 8));
      }
      #pragma unroll
      for (int fm = 0; fm < 4; ++fm)
        #pragma unroll
        for (int fn = 0; fn < 2; ++fn)
          acc[fm][fn] = MFMA16(af[fm], bfv[fn], acc[fm][fn]);
    }
    wait_lgkm0();
    __builtin_amdgcn_s_barrier();
  }

  #pragma unroll
  for (int fm = 0; fm < 4; ++fm) {
    int rowb = m0 + wr + fm * 16 + lg * 4;
    #pragma unroll
    for (int fn = 0; fn < 2; ++fn) {
      int col = ncol0 + wc + fn * 16 + l15;
      float bb = bias[col];
      #pragma unroll
      for (int r = 0; r < 4; ++r)
        Cout[(size_t)(rowb + r) * DM + col] = acc[fm][fn][r] + bb;
    }
  }
}

// ---- flash attention v3: QBLK=128, 4 waves x 32 q-rows, swapped QK^T (32x32),
// K fragments direct from global (L1-shared), V via LDS dbuf (32 KB),
// chunks of <=10 KV-tiles (544 blocks), f32 partials + combine.
__global__ __launch_bounds__(256, 2)
void attn_k(const bf16_t* __restrict__ Q, const bf16_t* __restrict__ K,
            const bf16_t* __restrict__ Vt, bf16_t* __restrict__ Z,
            float* __restrict__ Opart, float* __restrict__ mpart,
            float* __restrict__ lpart) {
  const int bid = blockIdx.x;
  const int h = bid & 15;
  const int g = bid >> 4;
  const int code = attn_map[g];
  const int qb = code >> 2, ci = code & 3;
  const int ntiles = 2 * qb + 2;
  const bool split = ntiles > 10;
  const int kt0 = 10 * ci;
  const int ktend = min(10 * ci + 9, 2 * qb + 1);
  const int q0 = qb * 128;
  const int hkv = h >> 2;
  const int t = threadIdx.x;
  const int lane = t & 63, w = t >> 6;
  const int l31 = lane & 31, hi = lane >> 5;
  const int qrow = q0 + w * 32 + l31;

  __shared__ bf16_t lV[2][128 * 64];  // [d][key], 8 slots of 8, slot ^= row&7

  bf16x8 qf[8];
  #pragma unroll
  for (int j = 0; j < 8; ++j)
    qf[j] = *(const bf16x8*)(Q + ((size_t)h * S + qrow) * DH + j * 16 + hi * 8);

  auto stageV = [&](int buf, int kt) {
    #pragma unroll
    for (int i = 0; i < 4; ++i) {
      int row = i * 32 + (t >> 3);
      int ss = (t & 7) ^ (row & 7);
      gload_lds16(Vt + ((size_t)hkv * DH + row) * S + kt * 64 + ss * 8,
                  (void*)(&lV[buf][0] + i * 2048 + t * 8));
    }
  };

  f32x16 oacc0 = {}, oacc1 = {}, oacc2 = {}, oacc3 = {};
  float m_run = -3.0e3f, l_run = 0.f;

  stageV(0, kt0);
  for (int kt = kt0; kt <= ktend; ++kt) {
    const int cur = (kt - kt0) & 1;
    if (kt < ktend) stageV(cur ^ 1, kt + 1);

    // QK^T: K fragments straight from global (coalesced 16B per lane)
    const bf16_t* kp = K + ((size_t)hkv * S + (size_t)kt * 64 + l31) * DH + hi * 8;
    f32x16 s0 = {}, s1 = {};
    __builtin_amdgcn_s_setprio(1);
    #pragma unroll
    for (int j = 0; j < 8; ++j) {
      bf16x8 k0 = *(const bf16x8*)(kp + j * 16);
      bf16x8 k1 = *(const bf16x8*)(kp + 32 * DH + j * 16);
      s0 = MFMA32(k0, qf[j], s0);
      s1 = MFMA32(k1, qf[j], s1);
    }
    __builtin_amdgcn_s_setprio(0);

    if (kt >= 2 * qb) {  // diag tiles: causal mask
      #pragma unroll
      for (int r = 0; r < 16; ++r) {
        int krow = kt * 64 + (r & 3) + 8 * (r >> 2) + 4 * hi;
        if (krow > qrow) s0[r] = -1e30f;
        if (krow + 32 > qrow) s1[r] = -1e30f;
      }
    }

    // row max (own 32 keys) then cross-half via permlane
    float mxa = s0[0], mxb = s0[1], mxc = s0[2], mxd = s0[3];
    #pragma unroll
    for (int r = 4; r < 16; r += 4) {
      mxa = fmaxf(mxa, s0[r]); mxb = fmaxf(mxb, s0[r + 1]);
      mxc = fmaxf(mxc, s0[r + 2]); mxd = fmaxf(mxd, s0[r + 3]);
    }
    #pragma unroll
    for (int r = 0; r < 16; r += 4) {
      mxa = fmaxf(mxa, s1[r]); mxb = fmaxf(mxb, s1[r + 1]);
      mxc = fmaxf(mxc, s1[r + 2]); mxd = fmaxf(mxd, s1[r + 3]);
    }
    float mfull = swapred_max(fmaxf(fmaxf(mxa, mxb), fmaxf(mxc, mxd)));

    float m_new, alpha;
    bool nore = __all(mfull - m_run <= 8.0f);  // defer-max
    if (nore) { m_new = m_run; alpha = 1.0f; }
    else { m_new = fmaxf(m_run, mfull); alpha = exp2f(m_run - m_new); }

    float psa = 0.f, psb = 0.f, psc = 0.f, psd = 0.f;
    #pragma unroll
    for (int r = 0; r < 16; r += 4) {
      s0[r] = exp2f(s0[r] - m_new); psa += s0[r];
      s0[r + 1] = exp2f(s0[r + 1] - m_new); psb += s0[r + 1];
      s0[r + 2] = exp2f(s0[r + 2] - m_new); psc += s0[r + 2];
      s0[r + 3] = exp2f(s0[r + 3] - m_new); psd += s0[r + 3];
    }
    #pragma unroll
    for (int r = 0; r < 16; r += 4) {
      s1[r] = exp2f(s1[r] - m_new); psa += s1[r];
      s1[r + 1] = exp2f(s1[r + 1] - m_new); psb += s1[r + 1];
      s1[r + 2] = exp2f(s1[r + 2] - m_new); psc += s1[r + 2];
      s1[r + 3] = exp2f(s1[r + 3] - m_new); psd += s1[r + 3];
    }
    float lt = swapred_sum((psa + psb) + (psc + psd));
    l_run = l_run * alpha + lt;
    m_run = m_new;

    if (!nore) {
      #pragma unroll
      for (int r = 0; r < 16; ++r) {
        int qs = (r & 3) + 8 * (r >> 2) + 4 * hi;
        float ar = __shfl(alpha, qs);
        oacc0[r] *= ar; oacc1[r] *= ar; oacc2[r] *= ar; oacc3[r] *= ar;
      }
    }

    // PV A-fragments fully in registers
    bf16x8 pa[4];
    pa[0] = packfrag(s0[0], s0[1], s0[2], s0[3], s0[4], s0[5], s0[6], s0[7]);
    pa[1] = packfrag(s0[8], s0[9], s0[10], s0[11], s0[12], s0[13], s0[14], s0[15]);
    pa[2] = packfrag(s1[0], s1[1], s1[2], s1[3], s1[4], s1[5], s1[6], s1[7]);
    pa[3] = packfrag(s1[8], s1[9], s1[10], s1[11], s1[12], s1[13], s1[14], s1[15]);

    wait_vmcnt<0>();                 // my V(kt+1) writes landed
    __builtin_amdgcn_s_barrier();    // everyone's landed; lV[cur] ready since last iter

    __builtin_amdgcn_s_setprio(1);
#define PVBLK(OA, db) { \
    int dr = (db) * 32 + l31; \
    _Pragma("unroll") \
    for (int ks = 0; ks < 4; ++ks) { \
      int sIdx = ks * 2 + hi; \
      bf16x8 vf = *(const bf16x8*)(&lV[cur][0] + dr * 64 + ((sIdx ^ (dr & 7)) * 8)); \
      OA = MFMA32(pa[ks], vf, OA); \
    } }
    PVBLK(oacc0, 0)
    PVBLK(oacc1, 1)
    PVBLK(oacc2, 2)
    PVBLK(oacc3, 3)
#undef PVBLK
    __builtin_amdgcn_s_setprio(0);
    wait_lgkm0();
    __builtin_amdgcn_s_barrier();    // all reads done; safe to overwrite next iter
  }

  if (!split) {
    float linv = 1.0f / l_run;
    #pragma unroll
    for (int r = 0; r < 16; ++r) {
      int qs = (r & 3) + 8 * (r >> 2) + 4 * hi;
      float lv = __shfl(linv, qs);
      int qg = q0 + w * 32 + qs;
      bf16_t* zp = Z + (size_t)qg * DM + h * DH + l31;
      zp[0]  = (bf16_t)(oacc0[r] * lv);
      zp[32] = (bf16_t)(oacc1[r] * lv);
      zp[64] = (bf16_t)(oacc2[r] * lv);
      zp[96] = (bf16_t)(oacc3[r] * lv);
    }
  } else {
    const int slot = h * 29 + sbase[qb] + ci;
    float* Op = Opart + (size_t)slot * 16384;
    #pragma unroll
    for (int r = 0; r < 16; ++r) {
      int qs = (r & 3) + 8 * (r >> 2) + 4 * hi;
      float* op = Op + (w * 32 + qs) * 128 + l31;
      op[0] = oacc0[r]; op[32] = oacc1[r]; op[64] = oacc2[r]; op[96] = oacc3[r];
    }
    if (lane < 32) {
      mpart[slot * 128 + w * 32 + l31] = m_run;
      lpart[slot * 128 + w * 32 + l31] = l_run;
    }
  }
}

// ---- combine: merge 2-4 chunks of each split unit (qb in 5..15)
__global__ void combine_k(const float* __restrict__ Opart, const float* __restrict__ mpart,
                          const float* __restrict__ lpart, bf16_t* __restrict__ Z) {
  int tid = blockIdx.x * 256 + threadIdx.x;  // 176 units * 16384
  int d = tid & 127;
  int q = (tid >> 7) & 127;
  int u = tid >> 14;       // 0..175
  int h = u / 11;
  int qb = 5 + (u - h * 11);
  int nc = (2 * qb + 11) / 10;
  int slot0 = h * 29 + sbase[qb];
  float M = -3.0e3f;
  #pragma unroll 4
  for (int c = 0; c < nc; ++c) M = fmaxf(M, mpart[(slot0 + c) * 128 + q]);
  float L = 0.f, O = 0.f;
  #pragma unroll 4
  for (int c = 0; c < nc; ++c) {
    float a = exp2f(mpart[(slot0 + c) * 128 + q] - M);
    L += a * lpart[(slot0 + c) * 128 + q];
    O += a * Opart[(size_t)(slot0 + c) * 16384 + q * 128 + d];
  }
  int qg = qb * 128 + q;
  Z[(size_t)qg * DM + h * DH + d] = (bf16_t)(O / L);
}

extern "C" void kernel_launch(void* const* d_in, const int* in_sizes, int n_in,
                              void* d_out, int out_size, void* d_ws, size_t ws_size,
                              hipStream_t stream) {
  (void)in_sizes; (void)n_in; (void)out_size; (void)ws_size;
  const float* Xq = (const float*)d_in[0];
  const float* Xk = (const float*)d_in[1];
  const float* Xv = (const float*)d_in[2];
  const float* WQ = (const float*)d_in[3];
  const float* bQ = (const float*)d_in[4];
  const float* WK = (const float*)d_in[5];
  const float* bK = (const float*)d_in[6];
  const float* WV = (const float*)d_in[7];
  const float* bV = (const float*)d_in[8];
  const float* WO = (const float*)d_in[9];
  const float* bO = (const float*)d_in[10];

  char* w = (char*)d_ws;
  float2* tab = (float2*)w;                // 1 MiB
  bf16_t* xq  = (bf16_t*)(w + (1 << 20));  // 8 MiB
  bf16_t* xk  = xq + 4194304;              // 8 MiB
  bf16_t* xv  = xk + 4194304;              // 8 MiB
  bf16_t* wqT = xv + 4194304;              // 8 MiB
  bf16_t* wkT = wqT + 4194304;             // 2 MiB
  bf16_t* wvT = wkT + 1048576;             // 2 MiB
  bf16_t* woT = wvT + 1048576;             // 8 MiB
  bf16_t* Qb  = woT + 4194304;             // 8 MiB
  bf16_t* Kb  = Qb + 4194304;              // 2 MiB
  bf16_t* Vtb = Kb + 1048576;              // 2 MiB  [4][128][2048]
  bf16_t* Zb  = Vtb + 1048576;             // 8 MiB
  // attn partials overlay xq..wqT (dead after proj): 464 slots * 64 KiB = 30.4 MiB
  float* Opart = (float*)xq;
  float* mpart = (float*)wkT;              // 464*128*4 = 237 KiB
  float* lpart = mpart + 464 * 128;

  rope_table_k<<<dim3(S), dim3(64), 0, stream>>>(tab);
  cvt3_k<<<dim3(12288), dim3(256), 0, stream>>>(Xq, Xk, Xv, xq, xk, xv);
  transpose_w_k<<<dim3(4, 64, 16), dim3(32, 8), 0, stream>>>(WQ, wqT, 2048, 128, 128, 0, 2048);
  transpose_wkv_k<<<dim3(4, 64, 8), dim3(32, 8), 0, stream>>>(WK, WV, wkT, wvT);
  transpose_w_k<<<dim3(64, 4, 16), dim3(32, 8), 0, stream>>>(WO, woT, 128, 2048, 0, 128, 2048);

  proj_gemm_k<<<dim3(48, 16), dim3(256), 0, stream>>>(xq, xk, xv, wqT, wkT, wvT,
                                                      bQ, bK, bV, Qb, Kb, Vtb);

  const float qscale = 1.4426950408889634f / sqrtf(128.0f);  // log2e / sqrt(D_HEAD)
  rope_qk_k<<<dim3(2560), dim3(256), 0, stream>>>(Qb, Kb, tab, qscale);

  attn_k<<<dim3(544), dim3(256), 0, stream>>>(Qb, Kb, Vtb, Zb, Opart, mpart, lpart);
  combine_k<<<dim3(11264), dim3(256), 0, stream>>>(Opart, mpart, lpart, Zb);

  gemm_o_k<<<dim3(32, 16), dim3(256), 0, stream>>>(Zb, woT, bO, (float*)d_out);
}

// Round 7
// 149.159 us; speedup vs baseline: 1.2201x; 1.2201x over previous
//
#include <hip/hip_runtime.h>
#include <hip/hip_bf16.h>
#include <stdint.h>
#include <math.h>

typedef __bf16 bf16_t;
typedef __attribute__((ext_vector_type(8))) __bf16 bf16x8;
typedef __attribute__((ext_vector_type(4))) __bf16 bf16x4;
typedef __attribute__((ext_vector_type(4))) float f32x4;
typedef __attribute__((ext_vector_type(16))) float f32x16;
typedef unsigned int uint2v __attribute__((ext_vector_type(2)));

static constexpr int S = 2048;
static constexpr int DM = 2048;
static constexpr int NH = 16;
static constexpr int NKV = 4;
static constexpr int DH = 128;

#define MFMA16(a, b, c) __builtin_amdgcn_mfma_f32_16x16x32_bf16((a), (b), (c), 0, 0, 0)
#define MFMA32(a, b, c) __builtin_amdgcn_mfma_f32_32x32x16_bf16((a), (b), (c), 0, 0, 0)

__device__ __forceinline__ void gload_lds16(const void* g, void* l) {
  __builtin_amdgcn_global_load_lds((__attribute__((address_space(1))) void*)(g),
                                   (__attribute__((address_space(3))) void*)(l), 16, 0, 0);
}

template <int N>
__device__ __forceinline__ void wait_vmcnt() {
  asm volatile("s_waitcnt vmcnt(%0)" :: "n"(N) : "memory");
}
__device__ __forceinline__ void wait_lgkm0() {
  asm volatile("s_waitcnt lgkmcnt(0)" ::: "memory");
}

__device__ __forceinline__ unsigned cvtpk(float lo, float hi) {
  unsigned r;
  asm("v_cvt_pk_bf16_f32 %0, %1, %2" : "=v"(r) : "v"(lo), "v"(hi));
  return r;
}
__device__ __forceinline__ void plswap2(unsigned& a, unsigned& b) {
  uint2v r = __builtin_amdgcn_permlane32_swap(a, b, false, false);
  a = r[0]; b = r[1];
}
__device__ __forceinline__ float swapred_max(float x) {
  uint2v r = __builtin_amdgcn_permlane32_swap(__float_as_uint(x), __float_as_uint(x), false, false);
  return fmaxf(__uint_as_float(r[0]), __uint_as_float(r[1]));
}
__device__ __forceinline__ float swapred_sum(float x) {
  uint2v r = __builtin_amdgcn_permlane32_swap(__float_as_uint(x), __float_as_uint(x), false, false);
  return __uint_as_float(r[0]) + __uint_as_float(r[1]);
}
__device__ __forceinline__ bf16x8 packfrag(float a0, float a1, float a2, float a3,
                                           float a4, float a5, float a6, float a7) {
  unsigned w0 = cvtpk(a0, a1), w1 = cvtpk(a2, a3);
  unsigned w2 = cvtpk(a4, a5), w3 = cvtpk(a6, a7);
  plswap2(w0, w2); plswap2(w1, w3);
  union { unsigned u[4]; bf16x8 v; } u;
  u.u[0] = w0; u.u[1] = w1; u.u[2] = w2; u.u[3] = w3;
  return u.v;
}

// 61 chunks/head, code = (qb<<3)|ci, descending qb; chunk = up to 5 KV-tiles
__device__ const unsigned char attn_map[61] = {
  120,121,122,123,124,125,126, 112,113,114,115,116,117, 104,105,106,107,108,109,
  96,97,98,99,100,101, 88,89,90,91,92, 80,81,82,83,84, 72,73,74,75, 64,65,66,67,
  56,57,58,59, 48,49,50, 40,41,42, 32,33, 24,25, 16,17, 8, 0};
// partial-slot base per qb (split qbs 2..15; 59 slots/head)
__device__ const unsigned char sbase[16] = {0,0,0,2,4,6,9,12,16,20,24,29,34,40,46,52};

// ---- fused prep: rope table + f32->bf16 converts + all weight transposes
__global__ __launch_bounds__(256)
void prep_k(const float* __restrict__ Xq, const float* __restrict__ Xk,
            const float* __restrict__ Xv, const float* __restrict__ WQ,
            const float* __restrict__ WK, const float* __restrict__ WV,
            const float* __restrict__ WO, float2* __restrict__ tab,
            bf16_t* __restrict__ xq, bf16_t* __restrict__ xk, bf16_t* __restrict__ xv,
            bf16_t* __restrict__ wqT, bf16_t* __restrict__ wkT, bf16_t* __restrict__ wvT,
            bf16_t* __restrict__ woT) {
  __shared__ float tile[32][33];
  const int b = blockIdx.x, t = threadIdx.x;
  if (b < 512) {
    // RoPE table [2048][64] {sin, cos}
    int idx = b * 256 + t;
    int p = idx >> 6, j = idx & 63;
    double inv = exp2(-(double)j * 13.287712379549449 / 64.0);
    double ang = (double)p * inv;
    tab[idx] = make_float2((float)sin(ang), (float)cos(ang));
  } else if (b < 12800) {
    int i = ((b - 512) * 256 + t) * 4;
    const float* in; bf16_t* out; int off;
    if (i < 4194304) { in = Xq; out = xq; off = i; }
    else if (i < 8388608) { in = Xk; out = xk; off = i - 4194304; }
    else { in = Xv; out = xv; off = i - 8388608; }
    f32x4 v = *(const f32x4*)(in + off);
    bf16x4 o;
    o[0] = (bf16_t)v[0]; o[1] = (bf16_t)v[1]; o[2] = (bf16_t)v[2]; o[3] = (bf16_t)v[3];
    *(bf16x4*)(out + off) = o;
  } else if (b < 16896) {
    // WQ (16,2048,128) -> wqT[(h*128+c)*2048 + r]
    int b2 = b - 12800;
    int bx = b2 & 3, by = (b2 >> 2) & 63, bz = b2 >> 8;
    int c0 = bx * 32, r0 = by * 32;
    int tx = t & 31, ty = t >> 5;
    const float* src = WQ + (size_t)bz * 2048 * 128;
    #pragma unroll
    for (int j = 0; j < 32; j += 8)
      tile[ty + j][tx] = src[(size_t)(r0 + ty + j) * 128 + c0 + tx];
    __syncthreads();
    #pragma unroll
    for (int j = 0; j < 32; j += 8)
      wqT[(size_t)(bz * 128 + c0 + ty + j) * 2048 + r0 + tx] = (bf16_t)tile[tx][ty + j];
  } else if (b < 18944) {
    // WK / WV (4,2048,128) -> wkT/wvT[(g*128+c)*2048 + r]
    int b2 = b - 16896;
    int bx = b2 & 3, by = (b2 >> 2) & 63, bz = b2 >> 8;  // bz 0..7
    int g = bz & 3;
    const float* in = (bz < 4) ? WK : WV;
    bf16_t* out = (bz < 4) ? wkT : wvT;
    int c0 = bx * 32, r0 = by * 32;
    int tx = t & 31, ty = t >> 5;
    const float* src = in + (size_t)g * 2048 * 128;
    #pragma unroll
    for (int j = 0; j < 32; j += 8)
      tile[ty + j][tx] = src[(size_t)(r0 + ty + j) * 128 + c0 + tx];
    __syncthreads();
    #pragma unroll
    for (int j = 0; j < 32; j += 8)
      out[(size_t)(g * 128 + c0 + ty + j) * 2048 + r0 + tx] = (bf16_t)tile[tx][ty + j];
  } else {
    // WO (16,128,2048) -> woT[c*2048 + h*128 + r]
    int b2 = b - 18944;
    int bx = b2 & 63, by = (b2 >> 6) & 3, bz = b2 >> 8;
    int c0 = bx * 32, r0 = by * 32;
    int tx = t & 31, ty = t >> 5;
    const float* src = WO + (size_t)bz * 128 * 2048;
    #pragma unroll
    for (int j = 0; j < 32; j += 8)
      tile[ty + j][tx] = src[(size_t)(r0 + ty + j) * 2048 + c0 + tx];
    __syncthreads();
    #pragma unroll
    for (int j = 0; j < 32; j += 8)
      woT[(size_t)(c0 + ty + j) * 2048 + bz * 128 + r0 + tx] = (bf16_t)tile[tx][ty + j];
  }
}

// ---- fused vectorized NeoX rotary on Q [16][S][128] and K [4][S][128]
__global__ void rope_qk_k(bf16_t* __restrict__ Qb, bf16_t* __restrict__ Kb,
                          const float2* __restrict__ tab, float qscale) {
  int tid = blockIdx.x * 256 + threadIdx.x;
  int row = tid >> 4;
  int i = (tid & 15) * 4;
  bf16_t* base; float scale;
  if (row < NH * S) { base = Qb + (size_t)row * DH; scale = qscale; }
  else { base = Kb + (size_t)(row - NH * S) * DH; scale = 1.0f; }
  int p = row & (S - 1);
  bf16x4 lo = *(bf16x4*)(base + i);
  bf16x4 hi = *(bf16x4*)(base + i + 64);
  float4 t0 = *(const float4*)(tab + p * 64 + i);
  float4 t1 = *(const float4*)(tab + p * 64 + i + 2);
  float sv[4] = {t0.x, t0.z, t1.x, t1.z};
  float cv[4] = {t0.y, t0.w, t1.y, t1.w};
  bf16x4 nlo, nhi;
  #pragma unroll
  for (int j = 0; j < 4; ++j) {
    float a = (float)lo[j], b = (float)hi[j];
    nlo[j] = (bf16_t)((a * cv[j] - b * sv[j]) * scale);
    nhi[j] = (bf16_t)((b * cv[j] + a * sv[j]) * scale);
  }
  *(bf16x4*)(base + i) = nlo;
  *(bf16x4*)(base + i + 64) = nhi;
}

// ---- fused QKV projection GEMM (BM=128, BN=64, BK=64, 768 blocks)
__global__ __launch_bounds__(256)
void proj_gemm_k(const bf16_t* __restrict__ xq, const bf16_t* __restrict__ xk,
                 const bf16_t* __restrict__ xv, const bf16_t* __restrict__ wqT,
                 const bf16_t* __restrict__ wkT, const bf16_t* __restrict__ wvT,
                 const float* __restrict__ bQ, const float* __restrict__ bK,
                 const float* __restrict__ bV, bf16_t* __restrict__ Qb,
                 bf16_t* __restrict__ Kb, bf16_t* __restrict__ Vt) {
  const int nb = blockIdx.x;
  const int m0 = blockIdx.y * 128;
  const bf16_t* A; const bf16_t* B; const float* bias; bf16_t* dst; int ncol0;
  bool vmode = false;
  if (nb < 32)      { A = xq; B = wqT; bias = bQ; dst = Qb; ncol0 = nb * 64; }
  else if (nb < 40) { A = xk; B = wkT; bias = bK; dst = Kb; ncol0 = (nb - 32) * 64; }
  else              { A = xv; B = wvT; bias = bV; dst = Vt; ncol0 = (nb - 40) * 64; vmode = true; }
  const int K = 2048;
  const int t = threadIdx.x;
  const int lane = t & 63, w = t >> 6;
  const int l15 = lane & 15, lg = lane >> 4;
  const int wr = (w >> 1) * 64, wc = (w & 1) * 32;

  __shared__ bf16_t lA[2][128 * 64];
  __shared__ bf16_t lB[2][64 * 64];

  f32x4 acc[4][2] = {};
  const int srow = t >> 3;
  const int sslot = t & 7;

  auto stage = [&](int buf, int kt) {
    #pragma unroll
    for (int i = 0; i < 4; ++i) {
      int row = i * 32 + srow;
      int ss = sslot ^ (row & 7);
      gload_lds16(A + (size_t)(m0 + row) * K + kt * 64 + ss * 8,
                  (void*)(&lA[buf][0] + i * 2048 + t * 8));
    }
    #pragma unroll
    for (int i = 0; i < 2; ++i) {
      int row = i * 32 + srow;
      int ss = sslot ^ (row & 7);
      gload_lds16(B + (size_t)(ncol0 + row) * K + kt * 64 + ss * 8,
                  (void*)(&lB[buf][0] + i * 2048 + t * 8));
    }
  };

  const int nk = K >> 6;
  stage(0, 0);
  for (int kt = 0; kt < nk; ++kt) {
    const int cur = kt & 1;
    if (kt + 1 < nk) {
      stage(cur ^ 1, kt + 1);
      wait_vmcnt<6>();
    } else {
      wait_vmcnt<0>();
    }
    __builtin_amdgcn_s_barrier();
    #pragma unroll
    for (int kk = 0; kk < 2; ++kk) {
      bf16x8 af[4], bfv[2];
      #pragma unroll
      for (int f = 0; f < 4; ++f) {
        int row = wr + f * 16 + l15;
        int slot = kk * 4 + lg;
        af[f] = *(const bf16x8*)(&lA[cur][0] + row * 64 + ((slot ^ (row & 7)) * 8));
      }
      #pragma unroll
      for (int f = 0; f < 2; ++f) {
        int row = wc + f * 16 + l15;
        int slot = kk * 4 + lg;
        bfv[f] = *(const bf16x8*)(&lB[cur][0] + row * 64 + ((slot ^ (row & 7)) * 8));
      }
      #pragma unroll
      for (int fm = 0; fm < 4; ++fm)
        #pragma unroll
        for (int fn = 0; fn < 2; ++fn)
          acc[fm][fn] = MFMA16(af[fm], bfv[fn], acc[fm][fn]);
    }
    wait_lgkm0();
    __builtin_amdgcn_s_barrier();
  }

  #pragma unroll
  for (int fm = 0; fm < 4; ++fm) {
    int rowb = m0 + wr + fm * 16 + lg * 4;
    #pragma unroll
    for (int fn = 0; fn < 2; ++fn) {
      int col = ncol0 + wc + fn * 16 + l15;
      float bb = bias[col];
      if (vmode) {
        bf16x4 pk;
        #pragma unroll
        for (int r = 0; r < 4; ++r) pk[r] = (bf16_t)(acc[fm][fn][r] + bb);
        *(bf16x4*)(dst + (size_t)col * S + rowb) = pk;
      } else {
        #pragma unroll
        for (int r = 0; r < 4; ++r) {
          float v = acc[fm][fn][r] + bb;
          dst[((size_t)(col >> 7) * S + (rowb + r)) * DH + (col & 127)] = (bf16_t)v;
        }
      }
    }
  }
}

// ---- O-projection GEMM
__global__ __launch_bounds__(256)
void gemm_o_k(const bf16_t* __restrict__ A, const bf16_t* __restrict__ B,
              const float* __restrict__ bias, float* __restrict__ Cout) {
  const int ncol0 = blockIdx.x * 64;
  const int m0 = blockIdx.y * 128;
  const int K = 2048;
  const int t = threadIdx.x;
  const int lane = t & 63, w = t >> 6;
  const int l15 = lane & 15, lg = lane >> 4;
  const int wr = (w >> 1) * 64, wc = (w & 1) * 32;

  __shared__ bf16_t lA[2][128 * 64];
  __shared__ bf16_t lB[2][64 * 64];

  f32x4 acc[4][2] = {};
  const int srow = t >> 3;
  const int sslot = t & 7;

  auto stage = [&](int buf, int kt) {
    #pragma unroll
    for (int i = 0; i < 4; ++i) {
      int row = i * 32 + srow;
      int ss = sslot ^ (row & 7);
      gload_lds16(A + (size_t)(m0 + row) * K + kt * 64 + ss * 8,
                  (void*)(&lA[buf][0] + i * 2048 + t * 8));
    }
    #pragma unroll
    for (int i = 0; i < 2; ++i) {
      int row = i * 32 + srow;
      int ss = sslot ^ (row & 7);
      gload_lds16(B + (size_t)(ncol0 + row) * K + kt * 64 + ss * 8,
                  (void*)(&lB[buf][0] + i * 2048 + t * 8));
    }
  };

  const int nk = K >> 6;
  stage(0, 0);
  for (int kt = 0; kt < nk; ++kt) {
    const int cur = kt & 1;
    if (kt + 1 < nk) {
      stage(cur ^ 1, kt + 1);
      wait_vmcnt<6>();
    } else {
      wait_vmcnt<0>();
    }
    __builtin_amdgcn_s_barrier();
    #pragma unroll
    for (int kk = 0; kk < 2; ++kk) {
      bf16x8 af[4], bfv[2];
      #pragma unroll
      for (int f = 0; f < 4; ++f) {
        int row = wr + f * 16 + l15;
        int slot = kk * 4 + lg;
        af[f] = *(const bf16x8*)(&lA[cur][0] + row * 64 + ((slot ^ (row & 7)) * 8));
      }
      #pragma unroll
      for (int f = 0; f < 2; ++f) {
        int row = wc + f * 16 + l15;
        int slot = kk * 4 + lg;
        bfv[f] = *(const bf16x8*)(&lB[cur][0] + row * 64 + ((slot ^ (row & 7)) * 8));
      }
      #pragma unroll
      for (int fm = 0; fm < 4; ++fm)
        #pragma unroll
        for (int fn = 0; fn < 2; ++fn)
          acc[fm][fn] = MFMA16(af[fm], bfv[fn], acc[fm][fn]);
    }
    wait_lgkm0();
    __builtin_amdgcn_s_barrier();
  }

  #pragma unroll
  for (int fm = 0; fm < 4; ++fm) {
    int rowb = m0 + wr + fm * 16 + lg * 4;
    #pragma unroll
    for (int fn = 0; fn < 2; ++fn) {
      int col = ncol0 + wc + fn * 16 + l15;
      float bb = bias[col];
      #pragma unroll
      for (int r = 0; r < 4; ++r)
        Cout[(size_t)(rowb + r) * DM + col] = acc[fm][fn][r] + bb;
    }
  }
}

// ---- flash attention (R5 core): QBLK=128, 4 waves x 32 q-rows, swapped QK^T
// (32x32), in-register softmax, K+V LDS dbuf, counted vmcnt. Fine chunks of
// <=5 KV-tiles (976 blocks); split units write bf16 O-partials + f32 m/l.
__global__ __launch_bounds__(256, 2)
void attn_k(const bf16_t* __restrict__ Q, const bf16_t* __restrict__ K,
            const bf16_t* __restrict__ Vt, bf16_t* __restrict__ Z,
            bf16_t* __restrict__ Opart, float* __restrict__ mpart,
            float* __restrict__ lpart) {
  const int bid = blockIdx.x;
  const int h = bid & 15;
  const int g = bid >> 4;
  const int code = attn_map[g];
  const int qb = code >> 3, ci = code & 7;
  const bool split = qb >= 2;
  const int kt0 = 5 * ci;
  const int kteA = 5 * ci + 4, kteB = 2 * qb + 1;
  const int ktend = kteA < kteB ? kteA : kteB;
  const int q0 = qb * 128;
  const int hkv = h >> 2;
  const int t = threadIdx.x;
  const int lane = t & 63, w = t >> 6;
  const int l31 = lane & 31, hi = lane >> 5;
  const int qrow = q0 + w * 32 + l31;

  __shared__ bf16_t lK[2][64 * 128];  // [key][d], 16 slots of 8, slot ^= row&15
  __shared__ bf16_t lV[2][128 * 64];  // [d][key], 8 slots of 8, slot ^= row&7

  bf16x8 qf[8];
  #pragma unroll
  for (int j = 0; j < 8; ++j)
    qf[j] = *(const bf16x8*)(Q + ((size_t)h * S + qrow) * DH + j * 16 + hi * 8);

  auto stageKV = [&](int buf, int kt) {
    #pragma unroll
    for (int i = 0; i < 4; ++i) {
      int row = i * 16 + (t >> 4);
      int ss = (t & 15) ^ (row & 15);
      gload_lds16(K + ((size_t)hkv * S + kt * 64 + row) * DH + ss * 8,
                  (void*)(&lK[buf][0] + i * 2048 + t * 8));
    }
    #pragma unroll
    for (int i = 0; i < 4; ++i) {
      int row = i * 32 + (t >> 3);
      int ss = (t & 7) ^ (row & 7);
      gload_lds16(Vt + ((size_t)hkv * DH + row) * S + kt * 64 + ss * 8,
                  (void*)(&lV[buf][0] + i * 2048 + t * 8));
    }
  };

  f32x16 oacc0 = {}, oacc1 = {}, oacc2 = {}, oacc3 = {};
  float m_run = -3.0e3f, l_run = 0.f;

  stageKV(0, kt0);
  for (int kt = kt0; kt <= ktend; ++kt) {
    const int cur = (kt - kt0) & 1;
    if (kt < ktend) {
      stageKV(cur ^ 1, kt + 1);
      wait_vmcnt<8>();
    } else {
      wait_vmcnt<0>();
    }
    __builtin_amdgcn_s_barrier();

    // S^T = K_tile(64x128) * Q^T: lane holds q=l31; keys (r&3)+8*(r>>2)+4*hi
    f32x16 s0 = {}, s1 = {};
    __builtin_amdgcn_s_setprio(1);
    #pragma unroll
    for (int j = 0; j < 8; ++j) {
      int sIdx = j * 2 + hi;
      int r0 = l31;
      bf16x8 k0 = *(const bf16x8*)(&lK[cur][0] + r0 * 128 + ((sIdx ^ (r0 & 15)) * 8));
      s0 = MFMA32(k0, qf[j], s0);
      int r1 = 32 + l31;
      bf16x8 k1 = *(const bf16x8*)(&lK[cur][0] + r1 * 128 + ((sIdx ^ (r1 & 15)) * 8));
      s1 = MFMA32(k1, qf[j], s1);
    }
    __builtin_amdgcn_s_setprio(0);

    if (kt >= 2 * qb) {  // diag tiles: causal mask
      #pragma unroll
      for (int r = 0; r < 16; ++r) {
        int krow = kt * 64 + (r & 3) + 8 * (r >> 2) + 4 * hi;
        if (krow > qrow) s0[r] = -1e30f;
        if (krow + 32 > qrow) s1[r] = -1e30f;
      }
    }

    float mxa = s0[0], mxb = s0[1], mxc = s0[2], mxd = s0[3];
    #pragma unroll
    for (int r = 4; r < 16; r += 4) {
      mxa = fmaxf(mxa, s0[r]); mxb = fmaxf(mxb, s0[r + 1]);
      mxc = fmaxf(mxc, s0[r + 2]); mxd = fmaxf(mxd, s0[r + 3]);
    }
    #pragma unroll
    for (int r = 0; r < 16; r += 4) {
      mxa = fmaxf(mxa, s1[r]); mxb = fmaxf(mxb, s1[r + 1]);
      mxc = fmaxf(mxc, s1[r + 2]); mxd = fmaxf(mxd, s1[r + 3]);
    }
    float mfull = swapred_max(fmaxf(fmaxf(mxa, mxb), fmaxf(mxc, mxd)));

    float m_new, alpha;
    bool nore = __all(mfull - m_run <= 8.0f);  // defer-max
    if (nore) { m_new = m_run; alpha = 1.0f; }
    else { m_new = fmaxf(m_run, mfull); alpha = exp2f(m_run - m_new); }

    float psa = 0.f, psb = 0.f, psc = 0.f, psd = 0.f;
    #pragma unroll
    for (int r = 0; r < 16; r += 4) {
      s0[r] = exp2f(s0[r] - m_new); psa += s0[r];
      s0[r + 1] = exp2f(s0[r + 1] - m_new); psb += s0[r + 1];
      s0[r + 2] = exp2f(s0[r + 2] - m_new); psc += s0[r + 2];
      s0[r + 3] = exp2f(s0[r + 3] - m_new); psd += s0[r + 3];
    }
    #pragma unroll
    for (int r = 0; r < 16; r += 4) {
      s1[r] = exp2f(s1[r] - m_new); psa += s1[r];
      s1[r + 1] = exp2f(s1[r + 1] - m_new); psb += s1[r + 1];
      s1[r + 2] = exp2f(s1[r + 2] - m_new); psc += s1[r + 2];
      s1[r + 3] = exp2f(s1[r + 3] - m_new); psd += s1[r + 3];
    }
    float lt = swapred_sum((psa + psb) + (psc + psd));
    l_run = l_run * alpha + lt;
    m_run = m_new;

    if (!nore) {
      #pragma unroll
      for (int r = 0; r < 16; ++r) {
        int qs = (r & 3) + 8 * (r >> 2) + 4 * hi;
        float ar = __shfl(alpha, qs);
        oacc0[r] *= ar; oacc1[r] *= ar; oacc2[r] *= ar; oacc3[r] *= ar;
      }
    }

    bf16x8 pa[4];
    pa[0] = packfrag(s0[0], s0[1], s0[2], s0[3], s0[4], s0[5], s0[6], s0[7]);
    pa[1] = packfrag(s0[8], s0[9], s0[10], s0[11], s0[12], s0[13], s0[14], s0[15]);
    pa[2] = packfrag(s1[0], s1[1], s1[2], s1[3], s1[4], s1[5], s1[6], s1[7]);
    pa[3] = packfrag(s1[8], s1[9], s1[10], s1[11], s1[12], s1[13], s1[14], s1[15]);

    __builtin_amdgcn_s_setprio(1);
#define PVBLK(OA, db) { \
    int dr = (db) * 32 + l31; \
    _Pragma("unroll") \
    for (int ks = 0; ks < 4; ++ks) { \
      int sIdx = ks * 2 + hi; \
      bf16x8 vf = *(const bf16x8*)(&lV[cur][0] + dr * 64 + ((sIdx ^ (dr & 7)) * 8)); \
      OA = MFMA32(pa[ks], vf, OA); \
    } }
    PVBLK(oacc0, 0)
    PVBLK(oacc1, 1)
    PVBLK(oacc2, 2)
    PVBLK(oacc3, 3)
#undef PVBLK
    __builtin_amdgcn_s_setprio(0);
    wait_lgkm0();
    __builtin_amdgcn_s_barrier();
  }

  if (!split) {
    float linv = 1.0f / l_run;
    #pragma unroll
    for (int r = 0; r < 16; ++r) {
      int qs = (r & 3) + 8 * (r >> 2) + 4 * hi;
      float lv = __shfl(linv, qs);
      int qg = q0 + w * 32 + qs;
      bf16_t* zp = Z + (size_t)qg * DM + h * DH + l31;
      zp[0]  = (bf16_t)(oacc0[r] * lv);
      zp[32] = (bf16_t)(oacc1[r] * lv);
      zp[64] = (bf16_t)(oacc2[r] * lv);
      zp[96] = (bf16_t)(oacc3[r] * lv);
    }
  } else {
    const int slot = h * 59 + sbase[qb] + ci;
    bf16_t* Op = Opart + (size_t)slot * 16384;
    #pragma unroll
    for (int r = 0; r < 16; ++r) {
      int qs = (r & 3) + 8 * (r >> 2) + 4 * hi;
      bf16_t* op = Op + (w * 32 + qs) * 128 + l31;
      op[0]  = (bf16_t)oacc0[r];
      op[32] = (bf16_t)oacc1[r];
      op[64] = (bf16_t)oacc2[r];
      op[96] = (bf16_t)oacc3[r];
    }
    if (lane < 32) {
      mpart[slot * 128 + w * 32 + l31] = m_run;
      lpart[slot * 128 + w * 32 + l31] = l_run;
    }
  }
}

// ---- combine: merge 2-7 chunks of each split unit (qb in 2..15)
__global__ void combine_k(const bf16_t* __restrict__ Opart, const float* __restrict__ mpart,
                          const float* __restrict__ lpart, bf16_t* __restrict__ Z) {
  int tid = blockIdx.x * 256 + threadIdx.x;  // 224 units * 128 q * 32 d4
  int d4 = tid & 31;
  int q = (tid >> 5) & 127;
  int u = tid >> 12;           // 0..223
  int h = u / 14;
  int qb = 2 + (u - h * 14);
  int nc = (2 * qb + 6) / 5;   // ceil((2qb+2)/5)
  int slot0 = h * 59 + sbase[qb];
  float M = -3.0e3f;
  for (int c = 0; c < nc; ++c) M = fmaxf(M, mpart[(slot0 + c) * 128 + q]);
  float L = 0.f;
  float o0 = 0.f, o1 = 0.f, o2 = 0.f, o3 = 0.f;
  for (int c = 0; c < nc; ++c) {
    float a = exp2f(mpart[(slot0 + c) * 128 + q] - M);
    L += a * lpart[(slot0 + c) * 128 + q];
    bf16x4 ov = *(const bf16x4*)(Opart + (size_t)(slot0 + c) * 16384 + q * 128 + d4 * 4);
    o0 += a * (float)ov[0]; o1 += a * (float)ov[1];
    o2 += a * (float)ov[2]; o3 += a * (float)ov[3];
  }
  float inv = 1.0f / L;
  bf16x4 zv;
  zv[0] = (bf16_t)(o0 * inv); zv[1] = (bf16_t)(o1 * inv);
  zv[2] = (bf16_t)(o2 * inv); zv[3] = (bf16_t)(o3 * inv);
  int qg = qb * 128 + q;
  *(bf16x4*)(Z + (size_t)qg * DM + h * DH + d4 * 4) = zv;
}

extern "C" void kernel_launch(void* const* d_in, const int* in_sizes, int n_in,
                              void* d_out, int out_size, void* d_ws, size_t ws_size,
                              hipStream_t stream) {
  (void)in_sizes; (void)n_in; (void)out_size; (void)ws_size;
  const float* Xq = (const float*)d_in[0];
  const float* Xk = (const float*)d_in[1];
  const float* Xv = (const float*)d_in[2];
  const float* WQ = (const float*)d_in[3];
  const float* bQ = (const float*)d_in[4];
  const float* WK = (const float*)d_in[5];
  const float* bK = (const float*)d_in[6];
  const float* WV = (const float*)d_in[7];
  const float* bV = (const float*)d_in[8];
  const float* WO = (const float*)d_in[9];
  const float* bO = (const float*)d_in[10];

  char* w = (char*)d_ws;
  float2* tab = (float2*)w;                // 1 MiB (dead after rope_qk -> m/l overlay)
  bf16_t* xq  = (bf16_t*)(w + (1 << 20));  // 8 MiB
  bf16_t* xk  = xq + 4194304;              // 8 MiB
  bf16_t* xv  = xk + 4194304;              // 8 MiB
  bf16_t* wqT = xv + 4194304;              // 8 MiB
  bf16_t* wkT = wqT + 4194304;             // 2 MiB
  bf16_t* wvT = wkT + 1048576;             // 2 MiB
  bf16_t* woT = wvT + 1048576;             // 8 MiB
  bf16_t* Qb  = woT + 4194304;             // 8 MiB
  bf16_t* Kb  = Qb + 4194304;              // 2 MiB
  bf16_t* Vtb = Kb + 1048576;              // 2 MiB  [4][128][2048]
  bf16_t* Zb  = Vtb + 1048576;             // 8 MiB
  // attn partials overlay xq.. (dead after proj): 944 slots * 32 KiB = 30.9 MiB
  bf16_t* Opart = xq;
  float* mpart = (float*)tab;              // 944*128*4 * 2 = 966 KiB <= 1 MiB
  float* lpart = mpart + 944 * 128;

  prep_k<<<dim3(23040), dim3(256), 0, stream>>>(Xq, Xk, Xv, WQ, WK, WV, WO, tab,
                                                xq, xk, xv, wqT, wkT, wvT, woT);

  proj_gemm_k<<<dim3(48, 16), dim3(256), 0, stream>>>(xq, xk, xv, wqT, wkT, wvT,
                                                      bQ, bK, bV, Qb, Kb, Vtb);

  const float qscale = 1.4426950408889634f / sqrtf(128.0f);  // log2e / sqrt(D_HEAD)
  rope_qk_k<<<dim3(2560), dim3(256), 0, stream>>>(Qb, Kb, tab, qscale);

  attn_k<<<dim3(976), dim3(256), 0, stream>>>(Qb, Kb, Vtb, Zb, Opart, mpart, lpart);
  combine_k<<<dim3(3584), dim3(256), 0, stream>>>(Opart, mpart, lpart, Zb);

  gemm_o_k<<<dim3(32, 16), dim3(256), 0, stream>>>(Zb, woT, bO, (float*)d_out);
}

// Round 8
// 142.793 us; speedup vs baseline: 1.2744x; 1.0446x over previous
//
#include <hip/hip_runtime.h>
#include <hip/hip_bf16.h>
#include <stdint.h>
#include <math.h>

typedef __bf16 bf16_t;
typedef __attribute__((ext_vector_type(8))) __bf16 bf16x8;
typedef __attribute__((ext_vector_type(4))) __bf16 bf16x4;
typedef __attribute__((ext_vector_type(4))) float f32x4;
typedef __attribute__((ext_vector_type(16))) float f32x16;
typedef unsigned int uint2v __attribute__((ext_vector_type(2)));

static constexpr int S = 2048;
static constexpr int DM = 2048;
static constexpr int NH = 16;
static constexpr int NKV = 4;
static constexpr int DH = 128;

#define MFMA16(a, b, c) __builtin_amdgcn_mfma_f32_16x16x32_bf16((a), (b), (c), 0, 0, 0)
#define MFMA32(a, b, c) __builtin_amdgcn_mfma_f32_32x32x16_bf16((a), (b), (c), 0, 0, 0)

__device__ __forceinline__ void gload_lds16(const void* g, void* l) {
  __builtin_amdgcn_global_load_lds((__attribute__((address_space(1))) void*)(g),
                                   (__attribute__((address_space(3))) void*)(l), 16, 0, 0);
}

template <int N>
__device__ __forceinline__ void wait_vmcnt() {
  asm volatile("s_waitcnt vmcnt(%0)" :: "n"(N) : "memory");
}
__device__ __forceinline__ void wait_lgkm0() {
  asm volatile("s_waitcnt lgkmcnt(0)" ::: "memory");
}

__device__ __forceinline__ unsigned cvtpk(float lo, float hi) {
  unsigned r;
  asm("v_cvt_pk_bf16_f32 %0, %1, %2" : "=v"(r) : "v"(lo), "v"(hi));
  return r;
}
__device__ __forceinline__ void plswap2(unsigned& a, unsigned& b) {
  uint2v r = __builtin_amdgcn_permlane32_swap(a, b, false, false);
  a = r[0]; b = r[1];
}
__device__ __forceinline__ float swapred_max(float x) {
  uint2v r = __builtin_amdgcn_permlane32_swap(__float_as_uint(x), __float_as_uint(x), false, false);
  return fmaxf(__uint_as_float(r[0]), __uint_as_float(r[1]));
}
__device__ __forceinline__ float swapred_sum(float x) {
  uint2v r = __builtin_amdgcn_permlane32_swap(__float_as_uint(x), __float_as_uint(x), false, false);
  return __uint_as_float(r[0]) + __uint_as_float(r[1]);
}
__device__ __forceinline__ bf16x8 packfrag(float a0, float a1, float a2, float a3,
                                           float a4, float a5, float a6, float a7) {
  unsigned w0 = cvtpk(a0, a1), w1 = cvtpk(a2, a3);
  unsigned w2 = cvtpk(a4, a5), w3 = cvtpk(a6, a7);
  plswap2(w0, w2); plswap2(w1, w3);
  union { unsigned u[4]; bf16x8 v; } u;
  u.u[0] = w0; u.u[1] = w1; u.u[2] = w2; u.u[3] = w3;
  return u.v;
}

// 61 chunks/head, code = (qb<<3)|ci, descending qb; chunk = up to 5 KV-tiles
__device__ const unsigned char attn_map[61] = {
  120,121,122,123,124,125,126, 112,113,114,115,116,117, 104,105,106,107,108,109,
  96,97,98,99,100,101, 88,89,90,91,92, 80,81,82,83,84, 72,73,74,75, 64,65,66,67,
  56,57,58,59, 48,49,50, 40,41,42, 32,33, 24,25, 16,17, 8, 0};
// partial-slot base per qb (split qbs 2..15; 59 slots/head)
__device__ const unsigned char sbase[16] = {0,0,0,2,4,6,9,12,16,20,24,29,34,40,46,52};

// ---- fused prep: rope table + f32->bf16 converts + all weight transposes
__global__ __launch_bounds__(256)
void prep_k(const float* __restrict__ Xq, const float* __restrict__ Xk,
            const float* __restrict__ Xv, const float* __restrict__ WQ,
            const float* __restrict__ WK, const float* __restrict__ WV,
            const float* __restrict__ WO, float2* __restrict__ tab,
            bf16_t* __restrict__ xq, bf16_t* __restrict__ xk, bf16_t* __restrict__ xv,
            bf16_t* __restrict__ wqT, bf16_t* __restrict__ wkT, bf16_t* __restrict__ wvT,
            bf16_t* __restrict__ woT) {
  __shared__ float tile[32][33];
  const int b = blockIdx.x, t = threadIdx.x;
  if (b < 512) {
    int idx = b * 256 + t;
    int p = idx >> 6, j = idx & 63;
    double inv = exp2(-(double)j * 13.287712379549449 / 64.0);
    double ang = (double)p * inv;
    tab[idx] = make_float2((float)sin(ang), (float)cos(ang));
  } else if (b < 12800) {
    int i = ((b - 512) * 256 + t) * 4;
    const float* in; bf16_t* out; int off;
    if (i < 4194304) { in = Xq; out = xq; off = i; }
    else if (i < 8388608) { in = Xk; out = xk; off = i - 4194304; }
    else { in = Xv; out = xv; off = i - 8388608; }
    f32x4 v = *(const f32x4*)(in + off);
    bf16x4 o;
    o[0] = (bf16_t)v[0]; o[1] = (bf16_t)v[1]; o[2] = (bf16_t)v[2]; o[3] = (bf16_t)v[3];
    *(bf16x4*)(out + off) = o;
  } else if (b < 16896) {
    int b2 = b - 12800;
    int bx = b2 & 3, by = (b2 >> 2) & 63, bz = b2 >> 8;
    int c0 = bx * 32, r0 = by * 32;
    int tx = t & 31, ty = t >> 5;
    const float* src = WQ + (size_t)bz * 2048 * 128;
    #pragma unroll
    for (int j = 0; j < 32; j += 8)
      tile[ty + j][tx] = src[(size_t)(r0 + ty + j) * 128 + c0 + tx];
    __syncthreads();
    #pragma unroll
    for (int j = 0; j < 32; j += 8)
      wqT[(size_t)(bz * 128 + c0 + ty + j) * 2048 + r0 + tx] = (bf16_t)tile[tx][ty + j];
  } else if (b < 18944) {
    int b2 = b - 16896;
    int bx = b2 & 3, by = (b2 >> 2) & 63, bz = b2 >> 8;  // bz 0..7
    int g = bz & 3;
    const float* in = (bz < 4) ? WK : WV;
    bf16_t* out = (bz < 4) ? wkT : wvT;
    int c0 = bx * 32, r0 = by * 32;
    int tx = t & 31, ty = t >> 5;
    const float* src = in + (size_t)g * 2048 * 128;
    #pragma unroll
    for (int j = 0; j < 32; j += 8)
      tile[ty + j][tx] = src[(size_t)(r0 + ty + j) * 128 + c0 + tx];
    __syncthreads();
    #pragma unroll
    for (int j = 0; j < 32; j += 8)
      out[(size_t)(g * 128 + c0 + ty + j) * 2048 + r0 + tx] = (bf16_t)tile[tx][ty + j];
  } else {
    int b2 = b - 18944;
    int bx = b2 & 63, by = (b2 >> 6) & 3, bz = b2 >> 8;
    int c0 = bx * 32, r0 = by * 32;
    int tx = t & 31, ty = t >> 5;
    const float* src = WO + (size_t)bz * 128 * 2048;
    #pragma unroll
    for (int j = 0; j < 32; j += 8)
      tile[ty + j][tx] = src[(size_t)(r0 + ty + j) * 2048 + c0 + tx];
    __syncthreads();
    #pragma unroll
    for (int j = 0; j < 32; j += 8)
      woT[(size_t)(c0 + ty + j) * 2048 + bz * 128 + r0 + tx] = (bf16_t)tile[tx][ty + j];
  }
}

// ---- fused vectorized NeoX rotary on Q [16][S][128] and K [4][S][128]
__global__ void rope_qk_k(bf16_t* __restrict__ Qb, bf16_t* __restrict__ Kb,
                          const float2* __restrict__ tab, float qscale) {
  int tid = blockIdx.x * 256 + threadIdx.x;
  int row = tid >> 4;
  int i = (tid & 15) * 4;
  bf16_t* base; float scale;
  if (row < NH * S) { base = Qb + (size_t)row * DH; scale = qscale; }
  else { base = Kb + (size_t)(row - NH * S) * DH; scale = 1.0f; }
  int p = row & (S - 1);
  bf16x4 lo = *(bf16x4*)(base + i);
  bf16x4 hi = *(bf16x4*)(base + i + 64);
  float4 t0 = *(const float4*)(tab + p * 64 + i);
  float4 t1 = *(const float4*)(tab + p * 64 + i + 2);
  float sv[4] = {t0.x, t0.z, t1.x, t1.z};
  float cv[4] = {t0.y, t0.w, t1.y, t1.w};
  bf16x4 nlo, nhi;
  #pragma unroll
  for (int j = 0; j < 4; ++j) {
    float a = (float)lo[j], b = (float)hi[j];
    nlo[j] = (bf16_t)((a * cv[j] - b * sv[j]) * scale);
    nhi[j] = (bf16_t)((b * cv[j] + a * sv[j]) * scale);
  }
  *(bf16x4*)(base + i) = nlo;
  *(bf16x4*)(base + i + 64) = nhi;
}

// ---- fused QKV projection GEMM (BM=128, BN=64, BK=64, 768 blocks, 1-D grid
// with XCD-patch swizzle: each XCD owns a 12nb x 8m patch -> L2 working set
// ~7 MB instead of ~36 MB)
__global__ __launch_bounds__(256)
void proj_gemm_k(const bf16_t* __restrict__ xq, const bf16_t* __restrict__ xk,
                 const bf16_t* __restrict__ xv, const bf16_t* __restrict__ wqT,
                 const bf16_t* __restrict__ wkT, const bf16_t* __restrict__ wvT,
                 const float* __restrict__ bQ, const float* __restrict__ bK,
                 const float* __restrict__ bV, bf16_t* __restrict__ Qb,
                 bf16_t* __restrict__ Kb, bf16_t* __restrict__ Vt) {
  const int b = blockIdx.x;
  const int xcd = b & 7, idx = b >> 3;          // idx 0..95
  const int nb = (xcd & 3) * 12 + idx % 12;     // 0..47
  const int m0 = ((xcd >> 2) * 8 + idx / 12) * 128;
  const bf16_t* A; const bf16_t* B; const float* bias; bf16_t* dst; int ncol0;
  bool vmode = false;
  if (nb < 32)      { A = xq; B = wqT; bias = bQ; dst = Qb; ncol0 = nb * 64; }
  else if (nb < 40) { A = xk; B = wkT; bias = bK; dst = Kb; ncol0 = (nb - 32) * 64; }
  else              { A = xv; B = wvT; bias = bV; dst = Vt; ncol0 = (nb - 40) * 64; vmode = true; }
  const int K = 2048;
  const int t = threadIdx.x;
  const int lane = t & 63, w = t >> 6;
  const int l15 = lane & 15, lg = lane >> 4;
  const int wr = (w >> 1) * 64, wc = (w & 1) * 32;

  __shared__ bf16_t lA[2][128 * 64];
  __shared__ bf16_t lB[2][64 * 64];

  f32x4 acc[4][2] = {};
  const int srow = t >> 3;
  const int sslot = t & 7;

  auto stage = [&](int buf, int kt) {
    #pragma unroll
    for (int i = 0; i < 4; ++i) {
      int row = i * 32 + srow;
      int ss = sslot ^ (row & 7);
      gload_lds16(A + (size_t)(m0 + row) * K + kt * 64 + ss * 8,
                  (void*)(&lA[buf][0] + i * 2048 + t * 8));
    }
    #pragma unroll
    for (int i = 0; i < 2; ++i) {
      int row = i * 32 + srow;
      int ss = sslot ^ (row & 7);
      gload_lds16(B + (size_t)(ncol0 + row) * K + kt * 64 + ss * 8,
                  (void*)(&lB[buf][0] + i * 2048 + t * 8));
    }
  };

  const int nk = K >> 6;
  stage(0, 0);
  for (int kt = 0; kt < nk; ++kt) {
    const int cur = kt & 1;
    if (kt + 1 < nk) {
      stage(cur ^ 1, kt + 1);
      wait_vmcnt<6>();
    } else {
      wait_vmcnt<0>();
    }
    __builtin_amdgcn_s_barrier();
    #pragma unroll
    for (int kk = 0; kk < 2; ++kk) {
      bf16x8 af[4], bfv[2];
      #pragma unroll
      for (int f = 0; f < 4; ++f) {
        int row = wr + f * 16 + l15;
        int slot = kk * 4 + lg;
        af[f] = *(const bf16x8*)(&lA[cur][0] + row * 64 + ((slot ^ (row & 7)) * 8));
      }
      #pragma unroll
      for (int f = 0; f < 2; ++f) {
        int row = wc + f * 16 + l15;
        int slot = kk * 4 + lg;
        bfv[f] = *(const bf16x8*)(&lB[cur][0] + row * 64 + ((slot ^ (row & 7)) * 8));
      }
      #pragma unroll
      for (int fm = 0; fm < 4; ++fm)
        #pragma unroll
        for (int fn = 0; fn < 2; ++fn)
          acc[fm][fn] = MFMA16(af[fm], bfv[fn], acc[fm][fn]);
    }
    wait_lgkm0();
    __builtin_amdgcn_s_barrier();
  }

  #pragma unroll
  for (int fm = 0; fm < 4; ++fm) {
    int rowb = m0 + wr + fm * 16 + lg * 4;
    #pragma unroll
    for (int fn = 0; fn < 2; ++fn) {
      int col = ncol0 + wc + fn * 16 + l15;
      float bb = bias[col];
      if (vmode) {
        bf16x4 pk;
        #pragma unroll
        for (int r = 0; r < 4; ++r) pk[r] = (bf16_t)(acc[fm][fn][r] + bb);
        *(bf16x4*)(dst + (size_t)col * S + rowb) = pk;
      } else {
        #pragma unroll
        for (int r = 0; r < 4; ++r) {
          float v = acc[fm][fn][r] + bb;
          dst[((size_t)(col >> 7) * S + (rowb + r)) * DH + (col & 127)] = (bf16_t)v;
        }
      }
    }
  }
}

// ---- O-projection GEMM (512 blocks, XCD-patch swizzle 8nb x 8m per XCD)
__global__ __launch_bounds__(256)
void gemm_o_k(const bf16_t* __restrict__ A, const bf16_t* __restrict__ B,
              const float* __restrict__ bias, float* __restrict__ Cout) {
  const int b = blockIdx.x;
  const int xcd = b & 7, idx = b >> 3;          // idx 0..63
  const int ncol0 = ((xcd & 3) * 8 + (idx & 7)) * 64;
  const int m0 = (((xcd >> 2) * 8) + (idx >> 3)) * 128;
  const int K = 2048;
  const int t = threadIdx.x;
  const int lane = t & 63, w = t >> 6;
  const int l15 = lane & 15, lg = lane >> 4;
  const int wr = (w >> 1) * 64, wc = (w & 1) * 32;

  __shared__ bf16_t lA[2][128 * 64];
  __shared__ bf16_t lB[2][64 * 64];

  f32x4 acc[4][2] = {};
  const int srow = t >> 3;
  const int sslot = t & 7;

  auto stage = [&](int buf, int kt) {
    #pragma unroll
    for (int i = 0; i < 4; ++i) {
      int row = i * 32 + srow;
      int ss = sslot ^ (row & 7);
      gload_lds16(A + (size_t)(m0 + row) * K + kt * 64 + ss * 8,
                  (void*)(&lA[buf][0] + i * 2048 + t * 8));
    }
    #pragma unroll
    for (int i = 0; i < 2; ++i) {
      int row = i * 32 + srow;
      int ss = sslot ^ (row & 7);
      gload_lds16(B + (size_t)(ncol0 + row) * K + kt * 64 + ss * 8,
                  (void*)(&lB[buf][0] + i * 2048 + t * 8));
    }
  };

  const int nk = K >> 6;
  stage(0, 0);
  for (int kt = 0; kt < nk; ++kt) {
    const int cur = kt & 1;
    if (kt + 1 < nk) {
      stage(cur ^ 1, kt + 1);
      wait_vmcnt<6>();
    } else {
      wait_vmcnt<0>();
    }
    __builtin_amdgcn_s_barrier();
    #pragma unroll
    for (int kk = 0; kk < 2; ++kk) {
      bf16x8 af[4], bfv[2];
      #pragma unroll
      for (int f = 0; f < 4; ++f) {
        int row = wr + f * 16 + l15;
        int slot = kk * 4 + lg;
        af[f] = *(const bf16x8*)(&lA[cur][0] + row * 64 + ((slot ^ (row & 7)) * 8));
      }
      #pragma unroll
      for (int f = 0; f < 2; ++f) {
        int row = wc + f * 16 + l15;
        int slot = kk * 4 + lg;
        bfv[f] = *(const bf16x8*)(&lB[cur][0] + row * 64 + ((slot ^ (row & 7)) * 8));
      }
      #pragma unroll
      for (int fm = 0; fm < 4; ++fm)
        #pragma unroll
        for (int fn = 0; fn < 2; ++fn)
          acc[fm][fn] = MFMA16(af[fm], bfv[fn], acc[fm][fn]);
    }
    wait_lgkm0();
    __builtin_amdgcn_s_barrier();
  }

  #pragma unroll
  for (int fm = 0; fm < 4; ++fm) {
    int rowb = m0 + wr + fm * 16 + lg * 4;
    #pragma unroll
    for (int fn = 0; fn < 2; ++fn) {
      int col = ncol0 + wc + fn * 16 + l15;
      float bb = bias[col];
      #pragma unroll
      for (int r = 0; r < 4; ++r)
        Cout[(size_t)(rowb + r) * DM + col] = acc[fm][fn][r] + bb;
    }
  }
}

// ---- flash attention: QBLK=128, 4 waves x 32 q-rows, swapped QK^T (32x32),
// in-register softmax, K+V LDS dbuf, counted vmcnt. Chunks of <=5 KV-tiles
// (976 blocks); split units write bf16 O-partials + f32 m/l.
__global__ __launch_bounds__(256, 2)
void attn_k(const bf16_t* __restrict__ Q, const bf16_t* __restrict__ K,
            const bf16_t* __restrict__ Vt, bf16_t* __restrict__ Z,
            bf16_t* __restrict__ Opart, float* __restrict__ mpart,
            float* __restrict__ lpart) {
  const int bid = blockIdx.x;
  const int h = bid & 15;
  const int g = bid >> 4;
  const int code = attn_map[g];
  const int qb = code >> 3, ci = code & 7;
  const bool split = qb >= 2;
  const int kt0 = 5 * ci;
  const int kteA = 5 * ci + 4, kteB = 2 * qb + 1;
  const int ktend = kteA < kteB ? kteA : kteB;
  const int q0 = qb * 128;
  const int hkv = h >> 2;
  const int t = threadIdx.x;
  const int lane = t & 63, w = t >> 6;
  const int l31 = lane & 31, hi = lane >> 5;
  const int qrow = q0 + w * 32 + l31;

  __shared__ bf16_t lK[2][64 * 128];  // [key][d], 16 slots of 8, slot ^= row&15
  __shared__ bf16_t lV[2][128 * 64];  // [d][key], 8 slots of 8, slot ^= row&7

  bf16x8 qf[8];
  #pragma unroll
  for (int j = 0; j < 8; ++j)
    qf[j] = *(const bf16x8*)(Q + ((size_t)h * S + qrow) * DH + j * 16 + hi * 8);

  auto stageKV = [&](int buf, int kt) {
    #pragma unroll
    for (int i = 0; i < 4; ++i) {
      int row = i * 16 + (t >> 4);
      int ss = (t & 15) ^ (row & 15);
      gload_lds16(K + ((size_t)hkv * S + kt * 64 + row) * DH + ss * 8,
                  (void*)(&lK[buf][0] + i * 2048 + t * 8));
    }
    #pragma unroll
    for (int i = 0; i < 4; ++i) {
      int row = i * 32 + (t >> 3);
      int ss = (t & 7) ^ (row & 7);
      gload_lds16(Vt + ((size_t)hkv * DH + row) * S + kt * 64 + ss * 8,
                  (void*)(&lV[buf][0] + i * 2048 + t * 8));
    }
  };

  f32x16 oacc0 = {}, oacc1 = {}, oacc2 = {}, oacc3 = {};
  float m_run = -3.0e3f, l_run = 0.f;

  stageKV(0, kt0);
  for (int kt = kt0; kt <= ktend; ++kt) {
    const int cur = (kt - kt0) & 1;
    if (kt < ktend) {
      stageKV(cur ^ 1, kt + 1);
      wait_vmcnt<8>();
    } else {
      wait_vmcnt<0>();
    }
    __builtin_amdgcn_s_barrier();

    f32x16 s0 = {}, s1 = {};
    __builtin_amdgcn_s_setprio(1);
    #pragma unroll
    for (int j = 0; j < 8; ++j) {
      int sIdx = j * 2 + hi;
      int r0 = l31;
      bf16x8 k0 = *(const bf16x8*)(&lK[cur][0] + r0 * 128 + ((sIdx ^ (r0 & 15)) * 8));
      s0 = MFMA32(k0, qf[j], s0);
      int r1 = 32 + l31;
      bf16x8 k1 = *(const bf16x8*)(&lK[cur][0] + r1 * 128 + ((sIdx ^ (r1 & 15)) * 8));
      s1 = MFMA32(k1, qf[j], s1);
    }
    __builtin_amdgcn_s_setprio(0);

    if (kt >= 2 * qb) {  // diag tiles: causal mask
      #pragma unroll
      for (int r = 0; r < 16; ++r) {
        int krow = kt * 64 + (r & 3) + 8 * (r >> 2) + 4 * hi;
        if (krow > qrow) s0[r] = -1e30f;
        if (krow + 32 > qrow) s1[r] = -1e30f;
      }
    }

    float mxa = s0[0], mxb = s0[1], mxc = s0[2], mxd = s0[3];
    #pragma unroll
    for (int r = 4; r < 16; r += 4) {
      mxa = fmaxf(mxa, s0[r]); mxb = fmaxf(mxb, s0[r + 1]);
      mxc = fmaxf(mxc, s0[r + 2]); mxd = fmaxf(mxd, s0[r + 3]);
    }
    #pragma unroll
    for (int r = 0; r < 16; r += 4) {
      mxa = fmaxf(mxa, s1[r]); mxb = fmaxf(mxb, s1[r + 1]);
      mxc = fmaxf(mxc, s1[r + 2]); mxd = fmaxf(mxd, s1[r + 3]);
    }
    float mfull = swapred_max(fmaxf(fmaxf(mxa, mxb), fmaxf(mxc, mxd)));

    float m_new, alpha;
    bool nore = __all(mfull - m_run <= 8.0f);  // defer-max
    if (nore) { m_new = m_run; alpha = 1.0f; }
    else { m_new = fmaxf(m_run, mfull); alpha = exp2f(m_run - m_new); }

    float psa = 0.f, psb = 0.f, psc = 0.f, psd = 0.f;
    #pragma unroll
    for (int r = 0; r < 16; r += 4) {
      s0[r] = exp2f(s0[r] - m_new); psa += s0[r];
      s0[r + 1] = exp2f(s0[r + 1] - m_new); psb += s0[r + 1];
      s0[r + 2] = exp2f(s0[r + 2] - m_new); psc += s0[r + 2];
      s0[r + 3] = exp2f(s0[r + 3] - m_new); psd += s0[r + 3];
    }
    #pragma unroll
    for (int r = 0; r < 16; r += 4) {
      s1[r] = exp2f(s1[r] - m_new); psa += s1[r];
      s1[r + 1] = exp2f(s1[r + 1] - m_new); psb += s1[r + 1];
      s1[r + 2] = exp2f(s1[r + 2] - m_new); psc += s1[r + 2];
      s1[r + 3] = exp2f(s1[r + 3] - m_new); psd += s1[r + 3];
    }
    float lt = swapred_sum((psa + psb) + (psc + psd));
    l_run = l_run * alpha + lt;
    m_run = m_new;

    if (!nore) {
      #pragma unroll
      for (int r = 0; r < 16; ++r) {
        int qs = (r & 3) + 8 * (r >> 2) + 4 * hi;
        float ar = __shfl(alpha, qs);
        oacc0[r] *= ar; oacc1[r] *= ar; oacc2[r] *= ar; oacc3[r] *= ar;
      }
    }

    bf16x8 pa[4];
    pa[0] = packfrag(s0[0], s0[1], s0[2], s0[3], s0[4], s0[5], s0[6], s0[7]);
    pa[1] = packfrag(s0[8], s0[9], s0[10], s0[11], s0[12], s0[13], s0[14], s0[15]);
    pa[2] = packfrag(s1[0], s1[1], s1[2], s1[3], s1[4], s1[5], s1[6], s1[7]);
    pa[3] = packfrag(s1[8], s1[9], s1[10], s1[11], s1[12], s1[13], s1[14], s1[15]);

    __builtin_amdgcn_s_setprio(1);
#define PVBLK(OA, db) { \
    int dr = (db) * 32 + l31; \
    _Pragma("unroll") \
    for (int ks = 0; ks < 4; ++ks) { \
      int sIdx = ks * 2 + hi; \
      bf16x8 vf = *(const bf16x8*)(&lV[cur][0] + dr * 64 + ((sIdx ^ (dr & 7)) * 8)); \
      OA = MFMA32(pa[ks], vf, OA); \
    } }
    PVBLK(oacc0, 0)
    PVBLK(oacc1, 1)
    PVBLK(oacc2, 2)
    PVBLK(oacc3, 3)
#undef PVBLK
    __builtin_amdgcn_s_setprio(0);
    wait_lgkm0();
    __builtin_amdgcn_s_barrier();
  }

  if (!split) {
    float linv = 1.0f / l_run;
    #pragma unroll
    for (int r = 0; r < 16; ++r) {
      int qs = (r & 3) + 8 * (r >> 2) + 4 * hi;
      float lv = __shfl(linv, qs);
      int qg = q0 + w * 32 + qs;
      bf16_t* zp = Z + (size_t)qg * DM + h * DH + l31;
      zp[0]  = (bf16_t)(oacc0[r] * lv);
      zp[32] = (bf16_t)(oacc1[r] * lv);
      zp[64] = (bf16_t)(oacc2[r] * lv);
      zp[96] = (bf16_t)(oacc3[r] * lv);
    }
  } else {
    const int slot = h * 59 + sbase[qb] + ci;
    bf16_t* Op = Opart + (size_t)slot * 16384;
    #pragma unroll
    for (int r = 0; r < 16; ++r) {
      int qs = (r & 3) + 8 * (r >> 2) + 4 * hi;
      bf16_t* op = Op + (w * 32 + qs) * 128 + l31;
      op[0]  = (bf16_t)oacc0[r];
      op[32] = (bf16_t)oacc1[r];
      op[64] = (bf16_t)oacc2[r];
      op[96] = (bf16_t)oacc3[r];
    }
    if (lane < 32) {
      mpart[slot * 128 + w * 32 + l31] = m_run;
      lpart[slot * 128 + w * 32 + l31] = l_run;
    }
  }
}

// ---- combine: merge 2-7 chunks of each split unit (qb in 2..15)
__global__ void combine_k(const bf16_t* __restrict__ Opart, const float* __restrict__ mpart,
                          const float* __restrict__ lpart, bf16_t* __restrict__ Z) {
  int tid = blockIdx.x * 256 + threadIdx.x;  // 224 units * 128 q * 32 d4
  int d4 = tid & 31;
  int q = (tid >> 5) & 127;
  int u = tid >> 12;           // 0..223
  int h = u / 14;
  int qb = 2 + (u - h * 14);
  int nc = (2 * qb + 6) / 5;   // ceil((2qb+2)/5)
  int slot0 = h * 59 + sbase[qb];
  float M = -3.0e3f;
  for (int c = 0; c < nc; ++c) M = fmaxf(M, mpart[(slot0 + c) * 128 + q]);
  float L = 0.f;
  float o0 = 0.f, o1 = 0.f, o2 = 0.f, o3 = 0.f;
  for (int c = 0; c < nc; ++c) {
    float a = exp2f(mpart[(slot0 + c) * 128 + q] - M);
    L += a * lpart[(slot0 + c) * 128 + q];
    bf16x4 ov = *(const bf16x4*)(Opart + (size_t)(slot0 + c) * 16384 + q * 128 + d4 * 4);
    o0 += a * (float)ov[0]; o1 += a * (float)ov[1];
    o2 += a * (float)ov[2]; o3 += a * (float)ov[3];
  }
  float inv = 1.0f / L;
  bf16x4 zv;
  zv[0] = (bf16_t)(o0 * inv); zv[1] = (bf16_t)(o1 * inv);
  zv[2] = (bf16_t)(o2 * inv); zv[3] = (bf16_t)(o3 * inv);
  int qg = qb * 128 + q;
  *(bf16x4*)(Z + (size_t)qg * DM + h * DH + d4 * 4) = zv;
}

extern "C" void kernel_launch(void* const* d_in, const int* in_sizes, int n_in,
                              void* d_out, int out_size, void* d_ws, size_t ws_size,
                              hipStream_t stream) {
  (void)in_sizes; (void)n_in; (void)out_size; (void)ws_size;
  const float* Xq = (const float*)d_in[0];
  const float* Xk = (const float*)d_in[1];
  const float* Xv = (const float*)d_in[2];
  const float* WQ = (const float*)d_in[3];
  const float* bQ = (const float*)d_in[4];
  const float* WK = (const float*)d_in[5];
  const float* bK = (const float*)d_in[6];
  const float* WV = (const float*)d_in[7];
  const float* bV = (const float*)d_in[8];
  const float* WO = (const float*)d_in[9];
  const float* bO = (const float*)d_in[10];

  char* w = (char*)d_ws;
  float2* tab = (float2*)w;                // 1 MiB (dead after rope_qk -> m/l overlay)
  bf16_t* xq  = (bf16_t*)(w + (1 << 20));  // 8 MiB
  bf16_t* xk  = xq + 4194304;              // 8 MiB
  bf16_t* xv  = xk + 4194304;              // 8 MiB
  bf16_t* wqT = xv + 4194304;              // 8 MiB
  bf16_t* wkT = wqT + 4194304;             // 2 MiB
  bf16_t* wvT = wkT + 1048576;             // 2 MiB
  bf16_t* woT = wvT + 1048576;             // 8 MiB
  bf16_t* Qb  = woT + 4194304;             // 8 MiB
  bf16_t* Kb  = Qb + 4194304;              // 2 MiB
  bf16_t* Vtb = Kb + 1048576;              // 2 MiB  [4][128][2048]
  bf16_t* Zb  = Vtb + 1048576;             // 8 MiB
  // attn partials overlay xq.. (dead after proj): 944 slots * 32 KiB = 30.9 MiB
  bf16_t* Opart = xq;
  float* mpart = (float*)tab;              // 944*128*4 * 2 = 966 KiB <= 1 MiB
  float* lpart = mpart + 944 * 128;

  prep_k<<<dim3(23040), dim3(256), 0, stream>>>(Xq, Xk, Xv, WQ, WK, WV, WO, tab,
                                                xq, xk, xv, wqT, wkT, wvT, woT);

  proj_gemm_k<<<dim3(768), dim3(256), 0, stream>>>(xq, xk, xv, wqT, wkT, wvT,
                                                   bQ, bK, bV, Qb, Kb, Vtb);

  const float qscale = 1.4426950408889634f / sqrtf(128.0f);  // log2e / sqrt(D_HEAD)
  rope_qk_k<<<dim3(2560), dim3(256), 0, stream>>>(Qb, Kb, tab, qscale);

  attn_k<<<dim3(976), dim3(256), 0, stream>>>(Qb, Kb, Vtb, Zb, Opart, mpart, lpart);
  combine_k<<<dim3(3584), dim3(256), 0, stream>>>(Opart, mpart, lpart, Zb);

  gemm_o_k<<<dim3(512), dim3(256), 0, stream>>>(Zb, woT, bO, (float*)d_out);
}

// Round 9
// 138.382 us; speedup vs baseline: 1.3151x; 1.0319x over previous
//
#include <hip/hip_runtime.h>
#include <hip/hip_bf16.h>
#include <stdint.h>
#include <math.h>

typedef __bf16 bf16_t;
typedef __attribute__((ext_vector_type(8))) __bf16 bf16x8;
typedef __attribute__((ext_vector_type(4))) __bf16 bf16x4;
typedef __attribute__((ext_vector_type(4))) float f32x4;
typedef __attribute__((ext_vector_type(16))) float f32x16;
typedef unsigned int uint2v __attribute__((ext_vector_type(2)));

static constexpr int S = 2048;
static constexpr int DM = 2048;
static constexpr int NH = 16;
static constexpr int NKV = 4;
static constexpr int DH = 128;

#define MFMA16(a, b, c) __builtin_amdgcn_mfma_f32_16x16x32_bf16((a), (b), (c), 0, 0, 0)
#define MFMA32(a, b, c) __builtin_amdgcn_mfma_f32_32x32x16_bf16((a), (b), (c), 0, 0, 0)

__device__ __forceinline__ void gload_lds16(const void* g, void* l) {
  __builtin_amdgcn_global_load_lds((__attribute__((address_space(1))) void*)(g),
                                   (__attribute__((address_space(3))) void*)(l), 16, 0, 0);
}

template <int N>
__device__ __forceinline__ void wait_vmcnt() {
  asm volatile("s_waitcnt vmcnt(%0)" :: "n"(N) : "memory");
}
__device__ __forceinline__ void wait_lgkm0() {
  asm volatile("s_waitcnt lgkmcnt(0)" ::: "memory");
}

__device__ __forceinline__ unsigned cvtpk(float lo, float hi) {
  unsigned r;
  asm("v_cvt_pk_bf16_f32 %0, %1, %2" : "=v"(r) : "v"(lo), "v"(hi));
  return r;
}
__device__ __forceinline__ void plswap2(unsigned& a, unsigned& b) {
  uint2v r = __builtin_amdgcn_permlane32_swap(a, b, false, false);
  a = r[0]; b = r[1];
}
__device__ __forceinline__ float swapred_max(float x) {
  uint2v r = __builtin_amdgcn_permlane32_swap(__float_as_uint(x), __float_as_uint(x), false, false);
  return fmaxf(__uint_as_float(r[0]), __uint_as_float(r[1]));
}
__device__ __forceinline__ float swapred_sum(float x) {
  uint2v r = __builtin_amdgcn_permlane32_swap(__float_as_uint(x), __float_as_uint(x), false, false);
  return __uint_as_float(r[0]) + __uint_as_float(r[1]);
}
__device__ __forceinline__ bf16x8 packfrag(float a0, float a1, float a2, float a3,
                                           float a4, float a5, float a6, float a7) {
  unsigned w0 = cvtpk(a0, a1), w1 = cvtpk(a2, a3);
  unsigned w2 = cvtpk(a4, a5), w3 = cvtpk(a6, a7);
  plswap2(w0, w2); plswap2(w1, w3);
  union { unsigned u[4]; bf16x8 v; } u;
  u.u[0] = w0; u.u[1] = w1; u.u[2] = w2; u.u[3] = w3;
  return u.v;
}

// 51 chunks/head, code = (qb<<3)|ci; chunk = up to 3 iterations of 128 keys.
// 3-iter chunks first, then 2-iter, then 1-iter (descending makespan).
__device__ const unsigned char attn_map[51] = {
  120,121,122,123,124, 112,113,114,115,116, 104,105,106,107, 96,97,98,99,
  88,89,90,91, 80,81,82, 72,73,74, 64,65,66, 56,57, 48,49, 40,41, 32, 24, 16,
  108, 83, 58, 33, 8, 125, 100, 75, 50, 25, 0};
// partial-slot base per qb (split qbs 3..15; 48 slots/head)
__device__ const unsigned char sbase[16] = {0,0,0,0,2,4,6,9,12,15,19,23,27,32,37,42};

// ---- fused prep: rope table + f32->bf16 converts + all weight transposes
__global__ __launch_bounds__(256)
void prep_k(const float* __restrict__ Xq, const float* __restrict__ Xk,
            const float* __restrict__ Xv, const float* __restrict__ WQ,
            const float* __restrict__ WK, const float* __restrict__ WV,
            const float* __restrict__ WO, float2* __restrict__ tab,
            bf16_t* __restrict__ xq, bf16_t* __restrict__ xk, bf16_t* __restrict__ xv,
            bf16_t* __restrict__ wqT, bf16_t* __restrict__ wkT, bf16_t* __restrict__ wvT,
            bf16_t* __restrict__ woT) {
  __shared__ float tile[32][33];
  const int b = blockIdx.x, t = threadIdx.x;
  if (b < 512) {
    int idx = b * 256 + t;
    int p = idx >> 6, j = idx & 63;
    double inv = exp2(-(double)j * 13.287712379549449 / 64.0);
    double ang = (double)p * inv;
    tab[idx] = make_float2((float)sin(ang), (float)cos(ang));
  } else if (b < 12800) {
    int i = ((b - 512) * 256 + t) * 4;
    const float* in; bf16_t* out; int off;
    if (i < 4194304) { in = Xq; out = xq; off = i; }
    else if (i < 8388608) { in = Xk; out = xk; off = i - 4194304; }
    else { in = Xv; out = xv; off = i - 8388608; }
    f32x4 v = *(const f32x4*)(in + off);
    bf16x4 o;
    o[0] = (bf16_t)v[0]; o[1] = (bf16_t)v[1]; o[2] = (bf16_t)v[2]; o[3] = (bf16_t)v[3];
    *(bf16x4*)(out + off) = o;
  } else if (b < 16896) {
    int b2 = b - 12800;
    int bx = b2 & 3, by = (b2 >> 2) & 63, bz = b2 >> 8;
    int c0 = bx * 32, r0 = by * 32;
    int tx = t & 31, ty = t >> 5;
    const float* src = WQ + (size_t)bz * 2048 * 128;
    #pragma unroll
    for (int j = 0; j < 32; j += 8)
      tile[ty + j][tx] = src[(size_t)(r0 + ty + j) * 128 + c0 + tx];
    __syncthreads();
    #pragma unroll
    for (int j = 0; j < 32; j += 8)
      wqT[(size_t)(bz * 128 + c0 + ty + j) * 2048 + r0 + tx] = (bf16_t)tile[tx][ty + j];
  } else if (b < 18944) {
    int b2 = b - 16896;
    int bx = b2 & 3, by = (b2 >> 2) & 63, bz = b2 >> 8;  // bz 0..7
    int g = bz & 3;
    const float* in = (bz < 4) ? WK : WV;
    bf16_t* out = (bz < 4) ? wkT : wvT;
    int c0 = bx * 32, r0 = by * 32;
    int tx = t & 31, ty = t >> 5;
    const float* src = in + (size_t)g * 2048 * 128;
    #pragma unroll
    for (int j = 0; j < 32; j += 8)
      tile[ty + j][tx] = src[(size_t)(r0 + ty + j) * 128 + c0 + tx];
    __syncthreads();
    #pragma unroll
    for (int j = 0; j < 32; j += 8)
      out[(size_t)(g * 128 + c0 + ty + j) * 2048 + r0 + tx] = (bf16_t)tile[tx][ty + j];
  } else {
    int b2 = b - 18944;
    int bx = b2 & 63, by = (b2 >> 6) & 3, bz = b2 >> 8;
    int c0 = bx * 32, r0 = by * 32;
    int tx = t & 31, ty = t >> 5;
    const float* src = WO + (size_t)bz * 128 * 2048;
    #pragma unroll
    for (int j = 0; j < 32; j += 8)
      tile[ty + j][tx] = src[(size_t)(r0 + ty + j) * 2048 + c0 + tx];
    __syncthreads();
    #pragma unroll
    for (int j = 0; j < 32; j += 8)
      woT[(size_t)(c0 + ty + j) * 2048 + bz * 128 + r0 + tx] = (bf16_t)tile[tx][ty + j];
  }
}

// ---- fused vectorized NeoX rotary on Q [16][S][128] and K [4][S][128]
__global__ void rope_qk_k(bf16_t* __restrict__ Qb, bf16_t* __restrict__ Kb,
                          const float2* __restrict__ tab, float qscale) {
  int tid = blockIdx.x * 256 + threadIdx.x;
  int row = tid >> 4;
  int i = (tid & 15) * 4;
  bf16_t* base; float scale;
  if (row < NH * S) { base = Qb + (size_t)row * DH; scale = qscale; }
  else { base = Kb + (size_t)(row - NH * S) * DH; scale = 1.0f; }
  int p = row & (S - 1);
  bf16x4 lo = *(bf16x4*)(base + i);
  bf16x4 hi = *(bf16x4*)(base + i + 64);
  float4 t0 = *(const float4*)(tab + p * 64 + i);
  float4 t1 = *(const float4*)(tab + p * 64 + i + 2);
  float sv[4] = {t0.x, t0.z, t1.x, t1.z};
  float cv[4] = {t0.y, t0.w, t1.y, t1.w};
  bf16x4 nlo, nhi;
  #pragma unroll
  for (int j = 0; j < 4; ++j) {
    float a = (float)lo[j], b = (float)hi[j];
    nlo[j] = (bf16_t)((a * cv[j] - b * sv[j]) * scale);
    nhi[j] = (bf16_t)((b * cv[j] + a * sv[j]) * scale);
  }
  *(bf16x4*)(base + i) = nlo;
  *(bf16x4*)(base + i + 64) = nhi;
}

// ---- fused QKV projection GEMM (BM=128, BN=64, BK=64, 768 blocks, XCD-patch)
__global__ __launch_bounds__(256)
void proj_gemm_k(const bf16_t* __restrict__ xq, const bf16_t* __restrict__ xk,
                 const bf16_t* __restrict__ xv, const bf16_t* __restrict__ wqT,
                 const bf16_t* __restrict__ wkT, const bf16_t* __restrict__ wvT,
                 const float* __restrict__ bQ, const float* __restrict__ bK,
                 const float* __restrict__ bV, bf16_t* __restrict__ Qb,
                 bf16_t* __restrict__ Kb, bf16_t* __restrict__ Vt) {
  const int b = blockIdx.x;
  const int xcd = b & 7, idx = b >> 3;          // idx 0..95
  const int nb = (xcd & 3) * 12 + idx % 12;     // 0..47
  const int m0 = ((xcd >> 2) * 8 + idx / 12) * 128;
  const bf16_t* A; const bf16_t* B; const float* bias; bf16_t* dst; int ncol0;
  bool vmode = false;
  if (nb < 32)      { A = xq; B = wqT; bias = bQ; dst = Qb; ncol0 = nb * 64; }
  else if (nb < 40) { A = xk; B = wkT; bias = bK; dst = Kb; ncol0 = (nb - 32) * 64; }
  else              { A = xv; B = wvT; bias = bV; dst = Vt; ncol0 = (nb - 40) * 64; vmode = true; }
  const int K = 2048;
  const int t = threadIdx.x;
  const int lane = t & 63, w = t >> 6;
  const int l15 = lane & 15, lg = lane >> 4;
  const int wr = (w >> 1) * 64, wc = (w & 1) * 32;

  __shared__ bf16_t lA[2][128 * 64];
  __shared__ bf16_t lB[2][64 * 64];

  f32x4 acc[4][2] = {};
  const int srow = t >> 3;
  const int sslot = t & 7;

  auto stage = [&](int buf, int kt) {
    #pragma unroll
    for (int i = 0; i < 4; ++i) {
      int row = i * 32 + srow;
      int ss = sslot ^ (row & 7);
      gload_lds16(A + (size_t)(m0 + row) * K + kt * 64 + ss * 8,
                  (void*)(&lA[buf][0] + i * 2048 + t * 8));
    }
    #pragma unroll
    for (int i = 0; i < 2; ++i) {
      int row = i * 32 + srow;
      int ss = sslot ^ (row & 7);
      gload_lds16(B + (size_t)(ncol0 + row) * K + kt * 64 + ss * 8,
                  (void*)(&lB[buf][0] + i * 2048 + t * 8));
    }
  };

  const int nk = K >> 6;
  stage(0, 0);
  for (int kt = 0; kt < nk; ++kt) {
    const int cur = kt & 1;
    if (kt + 1 < nk) {
      stage(cur ^ 1, kt + 1);
      wait_vmcnt<6>();
    } else {
      wait_vmcnt<0>();
    }
    __builtin_amdgcn_s_barrier();
    #pragma unroll
    for (int kk = 0; kk < 2; ++kk) {
      bf16x8 af[4], bfv[2];
      #pragma unroll
      for (int f = 0; f < 4; ++f) {
        int row = wr + f * 16 + l15;
        int slot = kk * 4 + lg;
        af[f] = *(const bf16x8*)(&lA[cur][0] + row * 64 + ((slot ^ (row & 7)) * 8));
      }
      #pragma unroll
      for (int f = 0; f < 2; ++f) {
        int row = wc + f * 16 + l15;
        int slot = kk * 4 + lg;
        bfv[f] = *(const bf16x8*)(&lB[cur][0] + row * 64 + ((slot ^ (row & 7)) * 8));
      }
      #pragma unroll
      for (int fm = 0; fm < 4; ++fm)
        #pragma unroll
        for (int fn = 0; fn < 2; ++fn)
          acc[fm][fn] = MFMA16(af[fm], bfv[fn], acc[fm][fn]);
    }
    wait_lgkm0();
    __builtin_amdgcn_s_barrier();
  }

  #pragma unroll
  for (int fm = 0; fm < 4; ++fm) {
    int rowb = m0 + wr + fm * 16 + lg * 4;
    #pragma unroll
    for (int fn = 0; fn < 2; ++fn) {
      int col = ncol0 + wc + fn * 16 + l15;
      float bb = bias[col];
      if (vmode) {
        bf16x4 pk;
        #pragma unroll
        for (int r = 0; r < 4; ++r) pk[r] = (bf16_t)(acc[fm][fn][r] + bb);
        *(bf16x4*)(dst + (size_t)col * S + rowb) = pk;
      } else {
        #pragma unroll
        for (int r = 0; r < 4; ++r) {
          float v = acc[fm][fn][r] + bb;
          dst[((size_t)(col >> 7) * S + (rowb + r)) * DH + (col & 127)] = (bf16_t)v;
        }
      }
    }
  }
}

// ---- O-projection GEMM (512 blocks, XCD-patch swizzle 8nb x 8m per XCD)
__global__ __launch_bounds__(256)
void gemm_o_k(const bf16_t* __restrict__ A, const bf16_t* __restrict__ B,
              const float* __restrict__ bias, float* __restrict__ Cout) {
  const int b = blockIdx.x;
  const int xcd = b & 7, idx = b >> 3;          // idx 0..63
  const int ncol0 = ((xcd & 3) * 8 + (idx & 7)) * 64;
  const int m0 = (((xcd >> 2) * 8) + (idx >> 3)) * 128;
  const int K = 2048;
  const int t = threadIdx.x;
  const int lane = t & 63, w = t >> 6;
  const int l15 = lane & 15, lg = lane >> 4;
  const int wr = (w >> 1) * 64, wc = (w & 1) * 32;

  __shared__ bf16_t lA[2][128 * 64];
  __shared__ bf16_t lB[2][64 * 64];

  f32x4 acc[4][2] = {};
  const int srow = t >> 3;
  const int sslot = t & 7;

  auto stage = [&](int buf, int kt) {
    #pragma unroll
    for (int i = 0; i < 4; ++i) {
      int row = i * 32 + srow;
      int ss = sslot ^ (row & 7);
      gload_lds16(A + (size_t)(m0 + row) * K + kt * 64 + ss * 8,
                  (void*)(&lA[buf][0] + i * 2048 + t * 8));
    }
    #pragma unroll
    for (int i = 0; i < 2; ++i) {
      int row = i * 32 + srow;
      int ss = sslot ^ (row & 7);
      gload_lds16(B + (size_t)(ncol0 + row) * K + kt * 64 + ss * 8,
                  (void*)(&lB[buf][0] + i * 2048 + t * 8));
    }
  };

  const int nk = K >> 6;
  stage(0, 0);
  for (int kt = 0; kt < nk; ++kt) {
    const int cur = kt & 1;
    if (kt + 1 < nk) {
      stage(cur ^ 1, kt + 1);
      wait_vmcnt<6>();
    } else {
      wait_vmcnt<0>();
    }
    __builtin_amdgcn_s_barrier();
    #pragma unroll
    for (int kk = 0; kk < 2; ++kk) {
      bf16x8 af[4], bfv[2];
      #pragma unroll
      for (int f = 0; f < 4; ++f) {
        int row = wr + f * 16 + l15;
        int slot = kk * 4 + lg;
        af[f] = *(const bf16x8*)(&lA[cur][0] + row * 64 + ((slot ^ (row & 7)) * 8));
      }
      #pragma unroll
      for (int f = 0; f < 2; ++f) {
        int row = wc + f * 16 + l15;
        int slot = kk * 4 + lg;
        bfv[f] = *(const bf16x8*)(&lB[cur][0] + row * 64 + ((slot ^ (row & 7)) * 8));
      }
      #pragma unroll
      for (int fm = 0; fm < 4; ++fm)
        #pragma unroll
        for (int fn = 0; fn < 2; ++fn)
          acc[fm][fn] = MFMA16(af[fm], bfv[fn], acc[fm][fn]);
    }
    wait_lgkm0();
    __builtin_amdgcn_s_barrier();
  }

  #pragma unroll
  for (int fm = 0; fm < 4; ++fm) {
    int rowb = m0 + wr + fm * 16 + lg * 4;
    #pragma unroll
    for (int fn = 0; fn < 2; ++fn) {
      int col = ncol0 + wc + fn * 16 + l15;
      float bb = bias[col];
      #pragma unroll
      for (int r = 0; r < 4; ++r)
        Cout[(size_t)(rowb + r) * DM + col] = acc[fm][fn][r] + bb;
    }
  }
}

// ---- flash attention: QBLK=128, 4 waves x 32 q-rows, swapped QK^T (32x32),
// in-register softmax. KVBLK=128 per iteration, K+V single-buffered (64 KB),
// 3 barriers / 128 keys. Chunks of <=3 iterations (816 blocks); split units
// (qb>=3) write bf16 O-partials + f32 m/l.
__global__ __launch_bounds__(256, 2)
void attn_k(const bf16_t* __restrict__ Q, const bf16_t* __restrict__ K,
            const bf16_t* __restrict__ Vt, bf16_t* __restrict__ Z,
            bf16_t* __restrict__ Opart, float* __restrict__ mpart,
            float* __restrict__ lpart) {
  const int bid = blockIdx.x;
  const int h = bid & 15;
  const int g = bid >> 4;
  const int code = attn_map[g];
  const int qb = code >> 3, ci = code & 7;
  const bool split = qb >= 3;
  const int it0 = 3 * ci;
  const int itend = (3 * ci + 2 < qb) ? (3 * ci + 2) : qb;
  const int q0 = qb * 128;
  const int hkv = h >> 2;
  const int t = threadIdx.x;
  const int lane = t & 63, w = t >> 6;
  const int l31 = lane & 31, hi = lane >> 5;
  const int qrow = q0 + w * 32 + l31;

  __shared__ bf16_t lK[128 * 128];  // [key][d], 16 slots of 8 elems, slot ^= row&15
  __shared__ bf16_t lV[128 * 128];  // [d][key], 16 slots of 8 elems, slot ^= row&15

  bf16x8 qf[8];
  #pragma unroll
  for (int j = 0; j < 8; ++j)
    qf[j] = *(const bf16x8*)(Q + ((size_t)h * S + qrow) * DH + j * 16 + hi * 8);

  auto stageKV = [&](int it) {
    #pragma unroll
    for (int i = 0; i < 8; ++i) {
      int row = i * 16 + (t >> 4);
      int ss = (t & 15) ^ (row & 15);
      gload_lds16(K + ((size_t)hkv * S + it * 128 + row) * DH + ss * 8,
                  (void*)(lK + i * 2048 + t * 8));
    }
    #pragma unroll
    for (int i = 0; i < 8; ++i) {
      int row = i * 16 + (t >> 4);
      int ss = (t & 15) ^ (row & 15);
      gload_lds16(Vt + ((size_t)hkv * DH + row) * S + it * 128 + ss * 8,
                  (void*)(lV + i * 2048 + t * 8));
    }
  };

  f32x16 oacc0 = {}, oacc1 = {}, oacc2 = {}, oacc3 = {};
  float m_run = -3.0e3f, l_run = 0.f;
  const int msk = l31 & 15;

  for (int it = it0; it <= itend; ++it) {
    __builtin_amdgcn_s_barrier();   // (A) prev iter's LDS reads complete
    stageKV(it);
    wait_vmcnt<8>();                // my K writes landed (V's 8 still in flight)
    __builtin_amdgcn_s_barrier();   // (B) K tile complete

    // S^T: 4 key-groups of 32; lane holds q=l31, keys n*32+(r&3)+8*(r>>2)+4*hi
    f32x16 s0 = {}, s1 = {}, s2 = {}, s3 = {};
    __builtin_amdgcn_s_setprio(1);
#define QKG(SN, N) { \
    const bf16_t* rb = lK + ((N) * 32 + l31) * 128; \
    _Pragma("unroll") \
    for (int j = 0; j < 8; ++j) { \
      bf16x8 kf = *(const bf16x8*)(rb + (((j * 2 + hi) ^ msk) * 8)); \
      SN = MFMA32(kf, qf[j], SN); \
    } }
    QKG(s0, 0) QKG(s1, 1) QKG(s2, 2) QKG(s3, 3)
#undef QKG
    __builtin_amdgcn_s_setprio(0);

    if (it == qb) {  // diag: causal mask
#define MASKG(SN, N) { \
      _Pragma("unroll") \
      for (int r = 0; r < 16; ++r) { \
        int key = it * 128 + (N) * 32 + (r & 3) + 8 * (r >> 2) + 4 * hi; \
        if (key > qrow) SN[r] = -1e30f; \
      } }
      MASKG(s0, 0) MASKG(s1, 1) MASKG(s2, 2) MASKG(s3, 3)
#undef MASKG
    }

    // row max over 128 keys
    float mxa = fmaxf(fmaxf(s0[0], s1[0]), fmaxf(s2[0], s3[0]));
    float mxb = fmaxf(fmaxf(s0[1], s1[1]), fmaxf(s2[1], s3[1]));
    float mxc = fmaxf(fmaxf(s0[2], s1[2]), fmaxf(s2[2], s3[2]));
    float mxd = fmaxf(fmaxf(s0[3], s1[3]), fmaxf(s2[3], s3[3]));
    #pragma unroll
    for (int r = 4; r < 16; r += 4) {
      mxa = fmaxf(mxa, fmaxf(fmaxf(s0[r], s1[r]), fmaxf(s2[r], s3[r])));
      mxb = fmaxf(mxb, fmaxf(fmaxf(s0[r+1], s1[r+1]), fmaxf(s2[r+1], s3[r+1])));
      mxc = fmaxf(mxc, fmaxf(fmaxf(s0[r+2], s1[r+2]), fmaxf(s2[r+2], s3[r+2])));
      mxd = fmaxf(mxd, fmaxf(fmaxf(s0[r+3], s1[r+3]), fmaxf(s2[r+3], s3[r+3])));
    }
    float mfull = swapred_max(fmaxf(fmaxf(mxa, mxb), fmaxf(mxc, mxd)));

    float m_new, alpha;
    bool nore = __all(mfull - m_run <= 8.0f);  // defer-max
    if (nore) { m_new = m_run; alpha = 1.0f; }
    else { m_new = fmaxf(m_run, mfull); alpha = exp2f(m_run - m_new); }

    float psa = 0.f, psb = 0.f, psc = 0.f, psd = 0.f;
#define EXPG(SN) { \
    _Pragma("unroll") \
    for (int r = 0; r < 16; r += 4) { \
      SN[r] = exp2f(SN[r] - m_new); psa += SN[r]; \
      SN[r+1] = exp2f(SN[r+1] - m_new); psb += SN[r+1]; \
      SN[r+2] = exp2f(SN[r+2] - m_new); psc += SN[r+2]; \
      SN[r+3] = exp2f(SN[r+3] - m_new); psd += SN[r+3]; \
    } }
    EXPG(s0) EXPG(s1) EXPG(s2) EXPG(s3)
#undef EXPG
    float lt = swapred_sum((psa + psb) + (psc + psd));
    l_run = l_run * alpha + lt;
    m_run = m_new;

    if (!nore) {
      #pragma unroll
      for (int r = 0; r < 16; ++r) {
        int qs = (r & 3) + 8 * (r >> 2) + 4 * hi;
        float ar = __shfl(alpha, qs);
        oacc0[r] *= ar; oacc1[r] *= ar; oacc2[r] *= ar; oacc3[r] *= ar;
      }
    }

    // PV A-fragments in registers: pa[c] covers keys c*16..c*16+15
    bf16x8 pa[8];
    pa[0] = packfrag(s0[0], s0[1], s0[2], s0[3], s0[4], s0[5], s0[6], s0[7]);
    pa[1] = packfrag(s0[8], s0[9], s0[10], s0[11], s0[12], s0[13], s0[14], s0[15]);
    pa[2] = packfrag(s1[0], s1[1], s1[2], s1[3], s1[4], s1[5], s1[6], s1[7]);
    pa[3] = packfrag(s1[8], s1[9], s1[10], s1[11], s1[12], s1[13], s1[14], s1[15]);
    pa[4] = packfrag(s2[0], s2[1], s2[2], s2[3], s2[4], s2[5], s2[6], s2[7]);
    pa[5] = packfrag(s2[8], s2[9], s2[10], s2[11], s2[12], s2[13], s2[14], s2[15]);
    pa[6] = packfrag(s3[0], s3[1], s3[2], s3[3], s3[4], s3[5], s3[6], s3[7]);
    pa[7] = packfrag(s3[8], s3[9], s3[10], s3[11], s3[12], s3[13], s3[14], s3[15]);

    wait_vmcnt<0>();                // my V writes landed
    __builtin_amdgcn_s_barrier();   // (C) V tile complete

    __builtin_amdgcn_s_setprio(1);
#define PVG(OA, DB) { \
    const bf16_t* vb = lV + ((DB) * 32 + l31) * 128; \
    _Pragma("unroll") \
    for (int ks = 0; ks < 8; ++ks) { \
      bf16x8 vf = *(const bf16x8*)(vb + (((ks * 2 + hi) ^ msk) * 8)); \
      OA = MFMA32(pa[ks], vf, OA); \
    } }
    PVG(oacc0, 0) PVG(oacc1, 1) PVG(oacc2, 2) PVG(oacc3, 3)
#undef PVG
    __builtin_amdgcn_s_setprio(0);
    wait_lgkm0();                   // my PV reads done (barrier (A) gates reuse)
  }

  if (!split) {
    float linv = 1.0f / l_run;
    #pragma unroll
    for (int r = 0; r < 16; ++r) {
      int qs = (r & 3) + 8 * (r >> 2) + 4 * hi;
      float lv = __shfl(linv, qs);
      int qg = q0 + w * 32 + qs;
      bf16_t* zp = Z + (size_t)qg * DM + h * DH + l31;
      zp[0]  = (bf16_t)(oacc0[r] * lv);
      zp[32] = (bf16_t)(oacc1[r] * lv);
      zp[64] = (bf16_t)(oacc2[r] * lv);
      zp[96] = (bf16_t)(oacc3[r] * lv);
    }
  } else {
    const int slot = h * 48 + sbase[qb] + ci;
    bf16_t* Op = Opart + (size_t)slot * 16384;
    #pragma unroll
    for (int r = 0; r < 16; ++r) {
      int qs = (r & 3) + 8 * (r >> 2) + 4 * hi;
      bf16_t* op = Op + (w * 32 + qs) * 128 + l31;
      op[0]  = (bf16_t)oacc0[r];
      op[32] = (bf16_t)oacc1[r];
      op[64] = (bf16_t)oacc2[r];
      op[96] = (bf16_t)oacc3[r];
    }
    if (lane < 32) {
      mpart[slot * 128 + w * 32 + l31] = m_run;
      lpart[slot * 128 + w * 32 + l31] = l_run;
    }
  }
}

// ---- combine: merge 2-6 chunks of each split unit (qb in 3..15)
__global__ void combine_k(const bf16_t* __restrict__ Opart, const float* __restrict__ mpart,
                          const float* __restrict__ lpart, bf16_t* __restrict__ Z) {
  int tid = blockIdx.x * 256 + threadIdx.x;  // 208 units * 128 q * 32 d4 = 3328 blocks
  int d4 = tid & 31;
  int q = (tid >> 5) & 127;
  int u = tid >> 12;           // 0..207
  int h = u / 13;
  int qb = 3 + (u - h * 13);
  int nc = (qb + 3) / 3;       // ceil((qb+1)/3)
  int slot0 = h * 48 + sbase[qb];
  float M = -3.0e3f;
  for (int c = 0; c < nc; ++c) M = fmaxf(M, mpart[(slot0 + c) * 128 + q]);
  float L = 0.f;
  float o0 = 0.f, o1 = 0.f, o2 = 0.f, o3 = 0.f;
  for (int c = 0; c < nc; ++c) {
    float a = exp2f(mpart[(slot0 + c) * 128 + q] - M);
    L += a * lpart[(slot0 + c) * 128 + q];
    bf16x4 ov = *(const bf16x4*)(Opart + (size_t)(slot0 + c) * 16384 + q * 128 + d4 * 4);
    o0 += a * (float)ov[0]; o1 += a * (float)ov[1];
    o2 += a * (float)ov[2]; o3 += a * (float)ov[3];
  }
  float inv = 1.0f / L;
  bf16x4 zv;
  zv[0] = (bf16_t)(o0 * inv); zv[1] = (bf16_t)(o1 * inv);
  zv[2] = (bf16_t)(o2 * inv); zv[3] = (bf16_t)(o3 * inv);
  int qg = qb * 128 + q;
  *(bf16x4*)(Z + (size_t)qg * DM + h * DH + d4 * 4) = zv;
}

extern "C" void kernel_launch(void* const* d_in, const int* in_sizes, int n_in,
                              void* d_out, int out_size, void* d_ws, size_t ws_size,
                              hipStream_t stream) {
  (void)in_sizes; (void)n_in; (void)out_size; (void)ws_size;
  const float* Xq = (const float*)d_in[0];
  const float* Xk = (const float*)d_in[1];
  const float* Xv = (const float*)d_in[2];
  const float* WQ = (const float*)d_in[3];
  const float* bQ = (const float*)d_in[4];
  const float* WK = (const float*)d_in[5];
  const float* bK = (const float*)d_in[6];
  const float* WV = (const float*)d_in[7];
  const float* bV = (const float*)d_in[8];
  const float* WO = (const float*)d_in[9];
  const float* bO = (const float*)d_in[10];

  char* w = (char*)d_ws;
  float2* tab = (float2*)w;                // 1 MiB (dead after rope_qk -> m/l overlay)
  bf16_t* xq  = (bf16_t*)(w + (1 << 20));  // 8 MiB
  bf16_t* xk  = xq + 4194304;              // 8 MiB
  bf16_t* xv  = xk + 4194304;              // 8 MiB
  bf16_t* wqT = xv + 4194304;              // 8 MiB
  bf16_t* wkT = wqT + 4194304;             // 2 MiB
  bf16_t* wvT = wkT + 1048576;             // 2 MiB
  bf16_t* woT = wvT + 1048576;             // 8 MiB
  bf16_t* Qb  = woT + 4194304;             // 8 MiB
  bf16_t* Kb  = Qb + 4194304;              // 2 MiB
  bf16_t* Vtb = Kb + 1048576;              // 2 MiB  [4][128][2048]
  bf16_t* Zb  = Vtb + 1048576;             // 8 MiB
  // attn partials overlay xq..xv (dead after proj): 768 slots * 32 KiB = 24 MiB
  bf16_t* Opart = xq;
  float* mpart = (float*)tab;              // 768*128*4 * 2 = 786 KiB <= 1 MiB
  float* lpart = mpart + 768 * 128;

  prep_k<<<dim3(23040), dim3(256), 0, stream>>>(Xq, Xk, Xv, WQ, WK, WV, WO, tab,
                                                xq, xk, xv, wqT, wkT, wvT, woT);

  proj_gemm_k<<<dim3(768), dim3(256), 0, stream>>>(xq, xk, xv, wqT, wkT, wvT,
                                                   bQ, bK, bV, Qb, Kb, Vtb);

  const float qscale = 1.4426950408889634f / sqrtf(128.0f);  // log2e / sqrt(D_HEAD)
  rope_qk_k<<<dim3(2560), dim3(256), 0, stream>>>(Qb, Kb, tab, qscale);

  attn_k<<<dim3(816), dim3(256), 0, stream>>>(Qb, Kb, Vtb, Zb, Opart, mpart, lpart);
  combine_k<<<dim3(3328), dim3(256), 0, stream>>>(Opart, mpart, lpart, Zb);

  gemm_o_k<<<dim3(512), dim3(256), 0, stream>>>(Zb, woT, bO, (float*)d_out);
}

// Round 10
// 137.835 us; speedup vs baseline: 1.3203x; 1.0040x over previous
//
#include <hip/hip_runtime.h>
#include <hip/hip_bf16.h>
#include <stdint.h>
#include <math.h>

typedef __bf16 bf16_t;
typedef __attribute__((ext_vector_type(8))) __bf16 bf16x8;
typedef __attribute__((ext_vector_type(4))) __bf16 bf16x4;
typedef __attribute__((ext_vector_type(4))) float f32x4;
typedef __attribute__((ext_vector_type(16))) float f32x16;
typedef unsigned int uint2v __attribute__((ext_vector_type(2)));

static constexpr int S = 2048;
static constexpr int DM = 2048;
static constexpr int NH = 16;
static constexpr int NKV = 4;
static constexpr int DH = 128;

#define MFMA16(a, b, c) __builtin_amdgcn_mfma_f32_16x16x32_bf16((a), (b), (c), 0, 0, 0)
#define MFMA32(a, b, c) __builtin_amdgcn_mfma_f32_32x32x16_bf16((a), (b), (c), 0, 0, 0)

__device__ __forceinline__ void gload_lds16(const void* g, void* l) {
  __builtin_amdgcn_global_load_lds((__attribute__((address_space(1))) void*)(g),
                                   (__attribute__((address_space(3))) void*)(l), 16, 0, 0);
}

template <int N>
__device__ __forceinline__ void wait_vmcnt() {
  asm volatile("s_waitcnt vmcnt(%0)" :: "n"(N) : "memory");
}
__device__ __forceinline__ void wait_lgkm0() {
  asm volatile("s_waitcnt lgkmcnt(0)" ::: "memory");
}

__device__ __forceinline__ unsigned cvtpk(float lo, float hi) {
  unsigned r;
  asm("v_cvt_pk_bf16_f32 %0, %1, %2" : "=v"(r) : "v"(lo), "v"(hi));
  return r;
}
__device__ __forceinline__ void plswap2(unsigned& a, unsigned& b) {
  uint2v r = __builtin_amdgcn_permlane32_swap(a, b, false, false);
  a = r[0]; b = r[1];
}
__device__ __forceinline__ float swapred_max(float x) {
  uint2v r = __builtin_amdgcn_permlane32_swap(__float_as_uint(x), __float_as_uint(x), false, false);
  return fmaxf(__uint_as_float(r[0]), __uint_as_float(r[1]));
}
__device__ __forceinline__ float swapred_sum(float x) {
  uint2v r = __builtin_amdgcn_permlane32_swap(__float_as_uint(x), __float_as_uint(x), false, false);
  return __uint_as_float(r[0]) + __uint_as_float(r[1]);
}
__device__ __forceinline__ bf16x8 packfrag(float a0, float a1, float a2, float a3,
                                           float a4, float a5, float a6, float a7) {
  unsigned w0 = cvtpk(a0, a1), w1 = cvtpk(a2, a3);
  unsigned w2 = cvtpk(a4, a5), w3 = cvtpk(a6, a7);
  plswap2(w0, w2); plswap2(w1, w3);
  union { unsigned u[4]; bf16x8 v; } u;
  u.u[0] = w0; u.u[1] = w1; u.u[2] = w2; u.u[3] = w3;
  return u.v;
}

// 51 chunks/head, code = (qb<<3)|ci; chunk = up to 3 iterations of 128 keys.
__device__ const unsigned char attn_map[51] = {
  120,121,122,123,124, 112,113,114,115,116, 104,105,106,107, 96,97,98,99,
  88,89,90,91, 80,81,82, 72,73,74, 64,65,66, 56,57, 48,49, 40,41, 32, 24, 16,
  108, 83, 58, 33, 8, 125, 100, 75, 50, 25, 0};
// partial-slot base per qb (split qbs 3..15; 48 slots/head)
__device__ const unsigned char sbase[16] = {0,0,0,0,2,4,6,9,12,15,19,23,27,32,37,42};

// ---- fused prep: rope table + f32->bf16 converts + all weight transposes
__global__ __launch_bounds__(256)
void prep_k(const float* __restrict__ Xq, const float* __restrict__ Xk,
            const float* __restrict__ Xv, const float* __restrict__ WQ,
            const float* __restrict__ WK, const float* __restrict__ WV,
            const float* __restrict__ WO, float2* __restrict__ tab,
            bf16_t* __restrict__ xq, bf16_t* __restrict__ xk, bf16_t* __restrict__ xv,
            bf16_t* __restrict__ wqT, bf16_t* __restrict__ wkT, bf16_t* __restrict__ wvT,
            bf16_t* __restrict__ woT) {
  __shared__ float tile[32][33];
  const int b = blockIdx.x, t = threadIdx.x;
  if (b < 512) {
    int idx = b * 256 + t;
    int p = idx >> 6, j = idx & 63;
    double inv = exp2(-(double)j * 13.287712379549449 / 64.0);
    double ang = (double)p * inv;
    tab[idx] = make_float2((float)sin(ang), (float)cos(ang));
  } else if (b < 12800) {
    int i = ((b - 512) * 256 + t) * 4;
    const float* in; bf16_t* out; int off;
    if (i < 4194304) { in = Xq; out = xq; off = i; }
    else if (i < 8388608) { in = Xk; out = xk; off = i - 4194304; }
    else { in = Xv; out = xv; off = i - 8388608; }
    f32x4 v = *(const f32x4*)(in + off);
    bf16x4 o;
    o[0] = (bf16_t)v[0]; o[1] = (bf16_t)v[1]; o[2] = (bf16_t)v[2]; o[3] = (bf16_t)v[3];
    *(bf16x4*)(out + off) = o;
  } else if (b < 16896) {
    int b2 = b - 12800;
    int bx = b2 & 3, by = (b2 >> 2) & 63, bz = b2 >> 8;
    int c0 = bx * 32, r0 = by * 32;
    int tx = t & 31, ty = t >> 5;
    const float* src = WQ + (size_t)bz * 2048 * 128;
    #pragma unroll
    for (int j = 0; j < 32; j += 8)
      tile[ty + j][tx] = src[(size_t)(r0 + ty + j) * 128 + c0 + tx];
    __syncthreads();
    #pragma unroll
    for (int j = 0; j < 32; j += 8)
      wqT[(size_t)(bz * 128 + c0 + ty + j) * 2048 + r0 + tx] = (bf16_t)tile[tx][ty + j];
  } else if (b < 18944) {
    int b2 = b - 16896;
    int bx = b2 & 3, by = (b2 >> 2) & 63, bz = b2 >> 8;  // bz 0..7
    int g = bz & 3;
    const float* in = (bz < 4) ? WK : WV;
    bf16_t* out = (bz < 4) ? wkT : wvT;
    int c0 = bx * 32, r0 = by * 32;
    int tx = t & 31, ty = t >> 5;
    const float* src = in + (size_t)g * 2048 * 128;
    #pragma unroll
    for (int j = 0; j < 32; j += 8)
      tile[ty + j][tx] = src[(size_t)(r0 + ty + j) * 128 + c0 + tx];
    __syncthreads();
    #pragma unroll
    for (int j = 0; j < 32; j += 8)
      out[(size_t)(g * 128 + c0 + ty + j) * 2048 + r0 + tx] = (bf16_t)tile[tx][ty + j];
  } else {
    int b2 = b - 18944;
    int bx = b2 & 63, by = (b2 >> 6) & 3, bz = b2 >> 8;
    int c0 = bx * 32, r0 = by * 32;
    int tx = t & 31, ty = t >> 5;
    const float* src = WO + (size_t)bz * 128 * 2048;
    #pragma unroll
    for (int j = 0; j < 32; j += 8)
      tile[ty + j][tx] = src[(size_t)(r0 + ty + j) * 2048 + c0 + tx];
    __syncthreads();
    #pragma unroll
    for (int j = 0; j < 32; j += 8)
      woT[(size_t)(c0 + ty + j) * 2048 + bz * 128 + r0 + tx] = (bf16_t)tile[tx][ty + j];
  }
}

// ---- fused vectorized NeoX rotary on Q [16][S][128] and K [4][S][128]
__global__ void rope_qk_k(bf16_t* __restrict__ Qb, bf16_t* __restrict__ Kb,
                          const float2* __restrict__ tab, float qscale) {
  int tid = blockIdx.x * 256 + threadIdx.x;
  int row = tid >> 4;
  int i = (tid & 15) * 4;
  bf16_t* base; float scale;
  if (row < NH * S) { base = Qb + (size_t)row * DH; scale = qscale; }
  else { base = Kb + (size_t)(row - NH * S) * DH; scale = 1.0f; }
  int p = row & (S - 1);
  bf16x4 lo = *(bf16x4*)(base + i);
  bf16x4 hi = *(bf16x4*)(base + i + 64);
  float4 t0 = *(const float4*)(tab + p * 64 + i);
  float4 t1 = *(const float4*)(tab + p * 64 + i + 2);
  float sv[4] = {t0.x, t0.z, t1.x, t1.z};
  float cv[4] = {t0.y, t0.w, t1.y, t1.w};
  bf16x4 nlo, nhi;
  #pragma unroll
  for (int j = 0; j < 4; ++j) {
    float a = (float)lo[j], b = (float)hi[j];
    nlo[j] = (bf16_t)((a * cv[j] - b * sv[j]) * scale);
    nhi[j] = (bf16_t)((b * cv[j] + a * sv[j]) * scale);
  }
  *(bf16x4*)(base + i) = nlo;
  *(bf16x4*)(base + i + 64) = nhi;
}

// ---- fused QKV projection GEMM (BM=128, BN=64, BK=64, 768 blocks, XCD-patch)
__global__ __launch_bounds__(256)
void proj_gemm_k(const bf16_t* __restrict__ xq, const bf16_t* __restrict__ xk,
                 const bf16_t* __restrict__ xv, const bf16_t* __restrict__ wqT,
                 const bf16_t* __restrict__ wkT, const bf16_t* __restrict__ wvT,
                 const float* __restrict__ bQ, const float* __restrict__ bK,
                 const float* __restrict__ bV, bf16_t* __restrict__ Qb,
                 bf16_t* __restrict__ Kb, bf16_t* __restrict__ Vt) {
  const int b = blockIdx.x;
  const int xcd = b & 7, idx = b >> 3;          // idx 0..95
  const int nb = (xcd & 3) * 12 + idx % 12;     // 0..47
  const int m0 = ((xcd >> 2) * 8 + idx / 12) * 128;
  const bf16_t* A; const bf16_t* B; const float* bias; bf16_t* dst; int ncol0;
  bool vmode = false;
  if (nb < 32)      { A = xq; B = wqT; bias = bQ; dst = Qb; ncol0 = nb * 64; }
  else if (nb < 40) { A = xk; B = wkT; bias = bK; dst = Kb; ncol0 = (nb - 32) * 64; }
  else              { A = xv; B = wvT; bias = bV; dst = Vt; ncol0 = (nb - 40) * 64; vmode = true; }
  const int K = 2048;
  const int t = threadIdx.x;
  const int lane = t & 63, w = t >> 6;
  const int l15 = lane & 15, lg = lane >> 4;
  const int wr = (w >> 1) * 64, wc = (w & 1) * 32;

  __shared__ bf16_t lA[2][128 * 64];
  __shared__ bf16_t lB[2][64 * 64];

  f32x4 acc[4][2] = {};
  const int srow = t >> 3;
  const int sslot = t & 7;

  auto stage = [&](int buf, int kt) {
    #pragma unroll
    for (int i = 0; i < 4; ++i) {
      int row = i * 32 + srow;
      int ss = sslot ^ (row & 7);
      gload_lds16(A + (size_t)(m0 + row) * K + kt * 64 + ss * 8,
                  (void*)(&lA[buf][0] + i * 2048 + t * 8));
    }
    #pragma unroll
    for (int i = 0; i < 2; ++i) {
      int row = i * 32 + srow;
      int ss = sslot ^ (row & 7);
      gload_lds16(B + (size_t)(ncol0 + row) * K + kt * 64 + ss * 8,
                  (void*)(&lB[buf][0] + i * 2048 + t * 8));
    }
  };

  const int nk = K >> 6;
  stage(0, 0);
  for (int kt = 0; kt < nk; ++kt) {
    const int cur = kt & 1;
    if (kt + 1 < nk) {
      stage(cur ^ 1, kt + 1);
      wait_vmcnt<6>();
    } else {
      wait_vmcnt<0>();
    }
    __builtin_amdgcn_s_barrier();
    #pragma unroll
    for (int kk = 0; kk < 2; ++kk) {
      bf16x8 af[4], bfv[2];
      #pragma unroll
      for (int f = 0; f < 4; ++f) {
        int row = wr + f * 16 + l15;
        int slot = kk * 4 + lg;
        af[f] = *(const bf16x8*)(&lA[cur][0] + row * 64 + ((slot ^ (row & 7)) * 8));
      }
      #pragma unroll
      for (int f = 0; f < 2; ++f) {
        int row = wc + f * 16 + l15;
        int slot = kk * 4 + lg;
        bfv[f] = *(const bf16x8*)(&lB[cur][0] + row * 64 + ((slot ^ (row & 7)) * 8));
      }
      #pragma unroll
      for (int fm = 0; fm < 4; ++fm)
        #pragma unroll
        for (int fn = 0; fn < 2; ++fn)
          acc[fm][fn] = MFMA16(af[fm], bfv[fn], acc[fm][fn]);
    }
    wait_lgkm0();
    __builtin_amdgcn_s_barrier();
  }

  #pragma unroll
  for (int fm = 0; fm < 4; ++fm) {
    int rowb = m0 + wr + fm * 16 + lg * 4;
    #pragma unroll
    for (int fn = 0; fn < 2; ++fn) {
      int col = ncol0 + wc + fn * 16 + l15;
      float bb = bias[col];
      if (vmode) {
        bf16x4 pk;
        #pragma unroll
        for (int r = 0; r < 4; ++r) pk[r] = (bf16_t)(acc[fm][fn][r] + bb);
        *(bf16x4*)(dst + (size_t)col * S + rowb) = pk;
      } else {
        #pragma unroll
        for (int r = 0; r < 4; ++r) {
          float v = acc[fm][fn][r] + bb;
          dst[((size_t)(col >> 7) * S + (rowb + r)) * DH + (col & 127)] = (bf16_t)v;
        }
      }
    }
  }
}

// ---- O-projection GEMM (512 blocks, XCD-patch swizzle 8nb x 8m per XCD)
__global__ __launch_bounds__(256)
void gemm_o_k(const bf16_t* __restrict__ A, const bf16_t* __restrict__ B,
              const float* __restrict__ bias, float* __restrict__ Cout) {
  const int b = blockIdx.x;
  const int xcd = b & 7, idx = b >> 3;          // idx 0..63
  const int ncol0 = ((xcd & 3) * 8 + (idx & 7)) * 64;
  const int m0 = (((xcd >> 2) * 8) + (idx >> 3)) * 128;
  const int K = 2048;
  const int t = threadIdx.x;
  const int lane = t & 63, w = t >> 6;
  const int l15 = lane & 15, lg = lane >> 4;
  const int wr = (w >> 1) * 64, wc = (w & 1) * 32;

  __shared__ bf16_t lA[2][128 * 64];
  __shared__ bf16_t lB[2][64 * 64];

  f32x4 acc[4][2] = {};
  const int srow = t >> 3;
  const int sslot = t & 7;

  auto stage = [&](int buf, int kt) {
    #pragma unroll
    for (int i = 0; i < 4; ++i) {
      int row = i * 32 + srow;
      int ss = sslot ^ (row & 7);
      gload_lds16(A + (size_t)(m0 + row) * K + kt * 64 + ss * 8,
                  (void*)(&lA[buf][0] + i * 2048 + t * 8));
    }
    #pragma unroll
    for (int i = 0; i < 2; ++i) {
      int row = i * 32 + srow;
      int ss = sslot ^ (row & 7);
      gload_lds16(B + (size_t)(ncol0 + row) * K + kt * 64 + ss * 8,
                  (void*)(&lB[buf][0] + i * 2048 + t * 8));
    }
  };

  const int nk = K >> 6;
  stage(0, 0);
  for (int kt = 0; kt < nk; ++kt) {
    const int cur = kt & 1;
    if (kt + 1 < nk) {
      stage(cur ^ 1, kt + 1);
      wait_vmcnt<6>();
    } else {
      wait_vmcnt<0>();
    }
    __builtin_amdgcn_s_barrier();
    #pragma unroll
    for (int kk = 0; kk < 2; ++kk) {
      bf16x8 af[4], bfv[2];
      #pragma unroll
      for (int f = 0; f < 4; ++f) {
        int row = wr + f * 16 + l15;
        int slot = kk * 4 + lg;
        af[f] = *(const bf16x8*)(&lA[cur][0] + row * 64 + ((slot ^ (row & 7)) * 8));
      }
      #pragma unroll
      for (int f = 0; f < 2; ++f) {
        int row = wc + f * 16 + l15;
        int slot = kk * 4 + lg;
        bfv[f] = *(const bf16x8*)(&lB[cur][0] + row * 64 + ((slot ^ (row & 7)) * 8));
      }
      #pragma unroll
      for (int fm = 0; fm < 4; ++fm)
        #pragma unroll
        for (int fn = 0; fn < 2; ++fn)
          acc[fm][fn] = MFMA16(af[fm], bfv[fn], acc[fm][fn]);
    }
    wait_lgkm0();
    __builtin_amdgcn_s_barrier();
  }

  #pragma unroll
  for (int fm = 0; fm < 4; ++fm) {
    int rowb = m0 + wr + fm * 16 + lg * 4;
    #pragma unroll
    for (int fn = 0; fn < 2; ++fn) {
      int col = ncol0 + wc + fn * 16 + l15;
      float bb = bias[col];
      #pragma unroll
      for (int r = 0; r < 4; ++r)
        Cout[(size_t)(rowb + r) * DM + col] = acc[fm][fn][r] + bb;
    }
  }
}

// ---- flash attention: QBLK=128, 4 waves x 32 q-rows, swapped QK^T (32x32),
// in-register softmax, KVBLK=128 single-buffered, 3 barriers / 128 keys.
// MFMA chains INTERLEAVED 4-wide (s0..s3 / oacc0..3) to run at issue rate.
__global__ __launch_bounds__(256, 2)
void attn_k(const bf16_t* __restrict__ Q, const bf16_t* __restrict__ K,
            const bf16_t* __restrict__ Vt, bf16_t* __restrict__ Z,
            bf16_t* __restrict__ Opart, float* __restrict__ mpart,
            float* __restrict__ lpart) {
  const int bid = blockIdx.x;
  const int h = bid & 15;
  const int g = bid >> 4;
  const int code = attn_map[g];
  const int qb = code >> 3, ci = code & 7;
  const bool split = qb >= 3;
  const int it0 = 3 * ci;
  const int itend = (3 * ci + 2 < qb) ? (3 * ci + 2) : qb;
  const int q0 = qb * 128;
  const int hkv = h >> 2;
  const int t = threadIdx.x;
  const int lane = t & 63, w = t >> 6;
  const int l31 = lane & 31, hi = lane >> 5;
  const int qrow = q0 + w * 32 + l31;

  __shared__ bf16_t lK[128 * 128];  // [key][d], 16 slots of 8 elems, slot ^= row&15
  __shared__ bf16_t lV[128 * 128];  // [d][key], 16 slots of 8 elems, slot ^= row&15

  bf16x8 qf[8];
  #pragma unroll
  for (int j = 0; j < 8; ++j)
    qf[j] = *(const bf16x8*)(Q + ((size_t)h * S + qrow) * DH + j * 16 + hi * 8);

  auto stageKV = [&](int it) {
    #pragma unroll
    for (int i = 0; i < 8; ++i) {
      int row = i * 16 + (t >> 4);
      int ss = (t & 15) ^ (row & 15);
      gload_lds16(K + ((size_t)hkv * S + it * 128 + row) * DH + ss * 8,
                  (void*)(lK + i * 2048 + t * 8));
    }
    #pragma unroll
    for (int i = 0; i < 8; ++i) {
      int row = i * 16 + (t >> 4);
      int ss = (t & 15) ^ (row & 15);
      gload_lds16(Vt + ((size_t)hkv * DH + row) * S + it * 128 + ss * 8,
                  (void*)(lV + i * 2048 + t * 8));
    }
  };

  f32x16 oacc0 = {}, oacc1 = {}, oacc2 = {}, oacc3 = {};
  float m_run = -3.0e3f, l_run = 0.f;
  const int msk = l31 & 15;
  const bf16_t* kb0 = lK + l31 * 128;
  const bf16_t* vb0 = lV + l31 * 128;

  for (int it = it0; it <= itend; ++it) {
    __builtin_amdgcn_s_barrier();   // (A) prev iter's LDS reads complete
    stageKV(it);
    wait_vmcnt<8>();                // my K writes landed (V's 8 still in flight)
    __builtin_amdgcn_s_barrier();   // (B) K tile complete

    // S^T: j-outer, 4 independent accumulator chains (issue-rate MFMA)
    f32x16 s0 = {}, s1 = {}, s2 = {}, s3 = {};
    __builtin_amdgcn_s_setprio(1);
    #pragma unroll
    for (int j = 0; j < 8; ++j) {
      int so = ((j * 2 + hi) ^ msk) * 8;
      bf16x8 k0 = *(const bf16x8*)(kb0 + so);
      bf16x8 k1 = *(const bf16x8*)(kb0 + 32 * 128 + so);
      bf16x8 k2 = *(const bf16x8*)(kb0 + 64 * 128 + so);
      bf16x8 k3 = *(const bf16x8*)(kb0 + 96 * 128 + so);
      s0 = MFMA32(k0, qf[j], s0);
      s1 = MFMA32(k1, qf[j], s1);
      s2 = MFMA32(k2, qf[j], s2);
      s3 = MFMA32(k3, qf[j], s3);
    }
    __builtin_amdgcn_s_setprio(0);

    if (it == qb) {  // diag: causal mask
#define MASKG(SN, N) { \
      _Pragma("unroll") \
      for (int r = 0; r < 16; ++r) { \
        int key = it * 128 + (N) * 32 + (r & 3) + 8 * (r >> 2) + 4 * hi; \
        if (key > qrow) SN[r] = -1e30f; \
      } }
      MASKG(s0, 0) MASKG(s1, 1) MASKG(s2, 2) MASKG(s3, 3)
#undef MASKG
    }

    // row max over 128 keys (max3-friendly triples)
    float mxa = fmaxf(fmaxf(s0[0], s1[0]), fmaxf(s2[0], s3[0]));
    float mxb = fmaxf(fmaxf(s0[1], s1[1]), fmaxf(s2[1], s3[1]));
    float mxc = fmaxf(fmaxf(s0[2], s1[2]), fmaxf(s2[2], s3[2]));
    float mxd = fmaxf(fmaxf(s0[3], s1[3]), fmaxf(s2[3], s3[3]));
    #pragma unroll
    for (int r = 4; r < 16; r += 4) {
      mxa = fmaxf(fmaxf(mxa, fmaxf(s0[r], s1[r])), fmaxf(s2[r], s3[r]));
      mxb = fmaxf(fmaxf(mxb, fmaxf(s0[r+1], s1[r+1])), fmaxf(s2[r+1], s3[r+1]));
      mxc = fmaxf(fmaxf(mxc, fmaxf(s0[r+2], s1[r+2])), fmaxf(s2[r+2], s3[r+2]));
      mxd = fmaxf(fmaxf(mxd, fmaxf(s0[r+3], s1[r+3])), fmaxf(s2[r+3], s3[r+3]));
    }
    float mfull = swapred_max(fmaxf(fmaxf(mxa, mxb), fmaxf(mxc, mxd)));

    float m_new, alpha;
    bool nore = __all(mfull - m_run <= 8.0f);  // defer-max
    if (nore) { m_new = m_run; alpha = 1.0f; }
    else { m_new = fmaxf(m_run, mfull); alpha = exp2f(m_run - m_new); }

    float psa = 0.f, psb = 0.f, psc = 0.f, psd = 0.f;
#define EXPG(SN) { \
    _Pragma("unroll") \
    for (int r = 0; r < 16; r += 4) { \
      SN[r] = exp2f(SN[r] - m_new); psa += SN[r]; \
      SN[r+1] = exp2f(SN[r+1] - m_new); psb += SN[r+1]; \
      SN[r+2] = exp2f(SN[r+2] - m_new); psc += SN[r+2]; \
      SN[r+3] = exp2f(SN[r+3] - m_new); psd += SN[r+3]; \
    } }
    EXPG(s0) EXPG(s1) EXPG(s2) EXPG(s3)
#undef EXPG
    float lt = swapred_sum((psa + psb) + (psc + psd));
    l_run = l_run * alpha + lt;
    m_run = m_new;

    if (!nore) {
      #pragma unroll
      for (int r = 0; r < 16; ++r) {
        int qs = (r & 3) + 8 * (r >> 2) + 4 * hi;
        float ar = __shfl(alpha, qs);
        oacc0[r] *= ar; oacc1[r] *= ar; oacc2[r] *= ar; oacc3[r] *= ar;
      }
    }

    // PV A-fragments in registers: pa[c] covers keys c*16..c*16+15
    bf16x8 pa[8];
    pa[0] = packfrag(s0[0], s0[1], s0[2], s0[3], s0[4], s0[5], s0[6], s0[7]);
    pa[1] = packfrag(s0[8], s0[9], s0[10], s0[11], s0[12], s0[13], s0[14], s0[15]);
    pa[2] = packfrag(s1[0], s1[1], s1[2], s1[3], s1[4], s1[5], s1[6], s1[7]);
    pa[3] = packfrag(s1[8], s1[9], s1[10], s1[11], s1[12], s1[13], s1[14], s1[15]);
    pa[4] = packfrag(s2[0], s2[1], s2[2], s2[3], s2[4], s2[5], s2[6], s2[7]);
    pa[5] = packfrag(s2[8], s2[9], s2[10], s2[11], s2[12], s2[13], s2[14], s2[15]);
    pa[6] = packfrag(s3[0], s3[1], s3[2], s3[3], s3[4], s3[5], s3[6], s3[7]);
    pa[7] = packfrag(s3[8], s3[9], s3[10], s3[11], s3[12], s3[13], s3[14], s3[15]);

    wait_vmcnt<0>();                // my V writes landed
    __builtin_amdgcn_s_barrier();   // (C) V tile complete

    // PV: ks-outer, 4 independent oacc chains
    __builtin_amdgcn_s_setprio(1);
    #pragma unroll
    for (int ks = 0; ks < 8; ++ks) {
      int so = ((ks * 2 + hi) ^ msk) * 8;
      bf16x8 v0 = *(const bf16x8*)(vb0 + so);
      bf16x8 v1 = *(const bf16x8*)(vb0 + 32 * 128 + so);
      bf16x8 v2 = *(const bf16x8*)(vb0 + 64 * 128 + so);
      bf16x8 v3 = *(const bf16x8*)(vb0 + 96 * 128 + so);
      oacc0 = MFMA32(pa[ks], v0, oacc0);
      oacc1 = MFMA32(pa[ks], v1, oacc1);
      oacc2 = MFMA32(pa[ks], v2, oacc2);
      oacc3 = MFMA32(pa[ks], v3, oacc3);
    }
    __builtin_amdgcn_s_setprio(0);
    wait_lgkm0();                   // my PV reads done (barrier (A) gates reuse)
  }

  if (!split) {
    float linv = 1.0f / l_run;
    #pragma unroll
    for (int r = 0; r < 16; ++r) {
      int qs = (r & 3) + 8 * (r >> 2) + 4 * hi;
      float lv = __shfl(linv, qs);
      int qg = q0 + w * 32 + qs;
      bf16_t* zp = Z + (size_t)qg * DM + h * DH + l31;
      zp[0]  = (bf16_t)(oacc0[r] * lv);
      zp[32] = (bf16_t)(oacc1[r] * lv);
      zp[64] = (bf16_t)(oacc2[r] * lv);
      zp[96] = (bf16_t)(oacc3[r] * lv);
    }
  } else {
    const int slot = h * 48 + sbase[qb] + ci;
    bf16_t* Op = Opart + (size_t)slot * 16384;
    #pragma unroll
    for (int r = 0; r < 16; ++r) {
      int qs = (r & 3) + 8 * (r >> 2) + 4 * hi;
      bf16_t* op = Op + (w * 32 + qs) * 128 + l31;
      op[0]  = (bf16_t)oacc0[r];
      op[32] = (bf16_t)oacc1[r];
      op[64] = (bf16_t)oacc2[r];
      op[96] = (bf16_t)oacc3[r];
    }
    if (lane < 32) {
      mpart[slot * 128 + w * 32 + l31] = m_run;
      lpart[slot * 128 + w * 32 + l31] = l_run;
    }
  }
}

// ---- combine: merge 2-6 chunks of each split unit (qb in 3..15)
__global__ void combine_k(const bf16_t* __restrict__ Opart, const float* __restrict__ mpart,
                          const float* __restrict__ lpart, bf16_t* __restrict__ Z) {
  int tid = blockIdx.x * 256 + threadIdx.x;  // 208 units * 128 q * 32 d4 = 3328 blocks
  int d4 = tid & 31;
  int q = (tid >> 5) & 127;
  int u = tid >> 12;           // 0..207
  int h = u / 13;
  int qb = 3 + (u - h * 13);
  int nc = (qb + 3) / 3;       // ceil((qb+1)/3)
  int slot0 = h * 48 + sbase[qb];
  float M = -3.0e3f;
  for (int c = 0; c < nc; ++c) M = fmaxf(M, mpart[(slot0 + c) * 128 + q]);
  float L = 0.f;
  float o0 = 0.f, o1 = 0.f, o2 = 0.f, o3 = 0.f;
  for (int c = 0; c < nc; ++c) {
    float a = exp2f(mpart[(slot0 + c) * 128 + q] - M);
    L += a * lpart[(slot0 + c) * 128 + q];
    bf16x4 ov = *(const bf16x4*)(Opart + (size_t)(slot0 + c) * 16384 + q * 128 + d4 * 4);
    o0 += a * (float)ov[0]; o1 += a * (float)ov[1];
    o2 += a * (float)ov[2]; o3 += a * (float)ov[3];
  }
  float inv = 1.0f / L;
  bf16x4 zv;
  zv[0] = (bf16_t)(o0 * inv); zv[1] = (bf16_t)(o1 * inv);
  zv[2] = (bf16_t)(o2 * inv); zv[3] = (bf16_t)(o3 * inv);
  int qg = qb * 128 + q;
  *(bf16x4*)(Z + (size_t)qg * DM + h * DH + d4 * 4) = zv;
}

extern "C" void kernel_launch(void* const* d_in, const int* in_sizes, int n_in,
                              void* d_out, int out_size, void* d_ws, size_t ws_size,
                              hipStream_t stream) {
  (void)in_sizes; (void)n_in; (void)out_size; (void)ws_size;
  const float* Xq = (const float*)d_in[0];
  const float* Xk = (const float*)d_in[1];
  const float* Xv = (const float*)d_in[2];
  const float* WQ = (const float*)d_in[3];
  const float* bQ = (const float*)d_in[4];
  const float* WK = (const float*)d_in[5];
  const float* bK = (const float*)d_in[6];
  const float* WV = (const float*)d_in[7];
  const float* bV = (const float*)d_in[8];
  const float* WO = (const float*)d_in[9];
  const float* bO = (const float*)d_in[10];

  char* w = (char*)d_ws;
  float2* tab = (float2*)w;                // 1 MiB (dead after rope_qk -> m/l overlay)
  bf16_t* xq  = (bf16_t*)(w + (1 << 20));  // 8 MiB
  bf16_t* xk  = xq + 4194304;              // 8 MiB
  bf16_t* xv  = xk + 4194304;              // 8 MiB
  bf16_t* wqT = xv + 4194304;              // 8 MiB
  bf16_t* wkT = wqT + 4194304;             // 2 MiB
  bf16_t* wvT = wkT + 1048576;             // 2 MiB
  bf16_t* woT = wvT + 1048576;             // 8 MiB
  bf16_t* Qb  = woT + 4194304;             // 8 MiB
  bf16_t* Kb  = Qb + 4194304;              // 2 MiB
  bf16_t* Vtb = Kb + 1048576;              // 2 MiB  [4][128][2048]
  bf16_t* Zb  = Vtb + 1048576;             // 8 MiB
  // attn partials overlay xq..xv (dead after proj): 768 slots * 32 KiB = 24 MiB
  bf16_t* Opart = xq;
  float* mpart = (float*)tab;              // 768*128*4 * 2 = 786 KiB <= 1 MiB
  float* lpart = mpart + 768 * 128;

  prep_k<<<dim3(23040), dim3(256), 0, stream>>>(Xq, Xk, Xv, WQ, WK, WV, WO, tab,
                                                xq, xk, xv, wqT, wkT, wvT, woT);

  proj_gemm_k<<<dim3(768), dim3(256), 0, stream>>>(xq, xk, xv, wqT, wkT, wvT,
                                                   bQ, bK, bV, Qb, Kb, Vtb);

  const float qscale = 1.4426950408889634f / sqrtf(128.0f);  // log2e / sqrt(D_HEAD)
  rope_qk_k<<<dim3(2560), dim3(256), 0, stream>>>(Qb, Kb, tab, qscale);

  attn_k<<<dim3(816), dim3(256), 0, stream>>>(Qb, Kb, Vtb, Zb, Opart, mpart, lpart);
  combine_k<<<dim3(3328), dim3(256), 0, stream>>>(Opart, mpart, lpart, Zb);

  gemm_o_k<<<dim3(512), dim3(256), 0, stream>>>(Zb, woT, bO, (float*)d_out);
}